// Round 12
// baseline (1050.008 us; speedup 1.0000x reference)
//
#include <hip/hip_runtime.h>

typedef __attribute__((ext_vector_type(8))) short bf16x8;
typedef __attribute__((ext_vector_type(4))) float f32x4;

__device__ __forceinline__ float lrelu(float x, float s) { return x >= 0.f ? x : s * x; }
__device__ __forceinline__ float b2f(unsigned short u) {
  union { unsigned int i; float f; } v; v.i = ((unsigned int)u) << 16; return v.f;
}
__device__ __forceinline__ float b2f_lo(unsigned int u) {
  union { unsigned int i; float f; } v; v.i = u << 16; return v.f;
}
__device__ __forceinline__ float b2f_hi(unsigned int u) {
  union { unsigned int i; float f; } v; v.i = u & 0xffff0000u; return v.f;
}
__device__ __forceinline__ unsigned short f2b(float f) {
  union { float f; unsigned int i; } v; v.f = f;
  unsigned int r = v.i + 0x7fffu + ((v.i >> 16) & 1u);
  return (unsigned short)(r >> 16);
}
__device__ __forceinline__ unsigned int fbits(float f) {
  union { float f; unsigned int i; } v; v.f = f; return v.i;
}
__device__ __forceinline__ float bitsf(unsigned int u) {
  union { unsigned int i; float f; } v; v.i = u; return v.f;
}

// Sense-reversing grid barrier. bar[0]=count, bar[1]=sense. All blocks must call.
// Safe across graph replays: count returns to 0; sense monotonic (memset re-arms).
__device__ __forceinline__ void gbar(int* bar, int nb) {
  __syncthreads();
  if (threadIdx.x == 0) {
    __threadfence();
    int s0 = __hip_atomic_load(&bar[1], __ATOMIC_RELAXED, __HIP_MEMORY_SCOPE_AGENT);
    int old = __hip_atomic_fetch_add(&bar[0], 1, __ATOMIC_ACQ_REL, __HIP_MEMORY_SCOPE_AGENT);
    if (old == nb - 1) {
      __hip_atomic_store(&bar[0], 0, __ATOMIC_RELAXED, __HIP_MEMORY_SCOPE_AGENT);
      __hip_atomic_fetch_add(&bar[1], 1, __ATOMIC_RELEASE, __HIP_MEMORY_SCOPE_AGENT);
    } else {
      while (__hip_atomic_load(&bar[1], __ATOMIC_ACQUIRE, __HIP_MEMORY_SCOPE_AGENT) == s0) {}
    }
    __threadfence();
  }
  __syncthreads();
}

// ---------------- fused CSR build + bf16 prep (one kernel, 4 grid barriers) ----------------
__global__ __launch_bounds__(256, 2) void k_csr(int* __restrict__ bar,
                                                int* __restrict__ cnt,
                                                const int* __restrict__ esrc,
                                                const int* __restrict__ edst,
                                                int E, int N,
                                                const float* __restrict__ x,
                                                unsigned short* __restrict__ xb,
                                                const float* __restrict__ W1,
                                                unsigned short* __restrict__ w1t,
                                                const float* __restrict__ W2,
                                                unsigned short* __restrict__ w2t,
                                                int* __restrict__ bsum,
                                                int* __restrict__ ptr,
                                                int* __restrict__ fill,
                                                int* __restrict__ srcs) {
  const int NB = gridDim.x;
  const int g0 = blockIdx.x * 256 + threadIdx.x;
  const int gs = NB * 256;
  const int n4 = N * 32;
  __shared__ int ws[4];
  __shared__ int bo_s;

  // phase 0: zero cnt + all bf16 conversions
  for (int i = g0; i < N; i += gs) cnt[i] = 0;
  for (int i = g0; i < n4; i += gs) {
    float4 v = ((const float4*)x)[i];
    ushort4 o;
    o.x = f2b(v.x); o.y = f2b(v.y); o.z = f2b(v.z); o.w = f2b(v.w);
    ((ushort4*)xb)[i] = o;
  }
  for (int i = g0; i < 256 * 128; i += gs) {
    int nn = i >> 7, k = i & 127;
    w1t[i] = f2b(W1[(size_t)k * 256 + nn]);
  }
  for (int i = g0; i < 256 * 256; i += gs) {
    int nn = i >> 8, k = i & 255;
    w2t[i] = f2b(W2[(size_t)k * 256 + nn]);
  }
  gbar(bar, NB);

  // phase 1: histogram of in-degrees
  for (int i = g0; i < E; i += gs) atomicAdd(&cnt[edst[i]], 1);
  gbar(bar, NB);

  // phase 2: super-block sums (+1 self-loop per node)
  const int B = (N + 1023) >> 10;
  const int t = threadIdx.x;
  if (blockIdx.x < B) {
    const int base = blockIdx.x * 1024;
    int s = 0;
#pragma unroll
    for (int i2 = 0; i2 < 4; ++i2) {
      int idx = base + t + i2 * 256;
      if (idx < N) s += cnt[idx] + 1;
    }
#pragma unroll
    for (int off = 1; off < 64; off <<= 1) s += __shfl_xor(s, off);
    const int lane = t & 63, w = t >> 6;
    if (lane == 0) ws[w] = s;
    __syncthreads();
    if (t == 0) bsum[blockIdx.x] = ws[0] + ws[1] + ws[2] + ws[3];
  }
  gbar(bar, NB);

  // phase 3: local scan + redundant wave-scan of bsum for global offset
  if (blockIdx.x < B) {
    if (t < 64) {
      int v = t < B ? bsum[t] : 0;
      int incl = v;
#pragma unroll
      for (int off = 1; off < 64; off <<= 1) {
        int u = __shfl_up(incl, off);
        if (t >= off) incl += u;
      }
      if (t == blockIdx.x) bo_s = incl - v;
      if (blockIdx.x == 0 && t == 63) ptr[N] = incl;
    }
    const int base = blockIdx.x * 1024 + t * 4;
    int v0 = base + 0 < N ? cnt[base + 0] + 1 : 0;
    int v1 = base + 1 < N ? cnt[base + 1] + 1 : 0;
    int v2 = base + 2 < N ? cnt[base + 2] + 1 : 0;
    int v3 = base + 3 < N ? cnt[base + 3] + 1 : 0;
    const int tsum = v0 + v1 + v2 + v3;
    const int lane = t & 63, w = t >> 6;
    int incl = tsum;
#pragma unroll
    for (int off = 1; off < 64; off <<= 1) {
      int u = __shfl_up(incl, off);
      if (lane >= off) incl += u;
    }
    if (lane == 63) ws[w] = incl;
    __syncthreads();
    int excl = bo_s + incl - tsum;
    for (int i = 0; i < w; ++i) excl += ws[i];
    if (base + 0 < N) { ptr[base + 0] = excl; fill[base + 0] = excl; }
    excl += v0;
    if (base + 1 < N) { ptr[base + 1] = excl; fill[base + 1] = excl; }
    excl += v1;
    if (base + 2 < N) { ptr[base + 2] = excl; fill[base + 2] = excl; }
    excl += v2;
    if (base + 3 < N) { ptr[base + 3] = excl; fill[base + 3] = excl; }
  }
  gbar(bar, NB);

  // phase 4: scatter (nontemporal stores: skip write-allocate RMW in L2)
  for (int i = g0; i < E + N; i += gs) {
    if (i < E) {
      int d = edst[i];
      int sv = esrc[i];
      int pos = atomicAdd(&fill[d], 1);
      __builtin_nontemporal_store(sv, &srcs[pos]);
    } else {
      int v = i - E;
      int pos = atomicAdd(&fill[v], 1);
      __builtin_nontemporal_store(v, &srcs[pos]);
    }
  }
}

// ---------------- bf16 MFMA GEMM + fused attention coefficients ----------------
__global__ __launch_bounds__(256) void k_mfma(const unsigned short* __restrict__ A,
                                              const unsigned short* __restrict__ BT,
                                              unsigned short* __restrict__ C,
                                              const float* __restrict__ as_,
                                              const float* __restrict__ ad_,
                                              float* __restrict__ als,
                                              float* __restrict__ ald,
                                              int M, int Nn, int K) {
  __shared__ unsigned int Asu[128 * 20];
  __shared__ unsigned int Bsu[128 * 20];
  const int tid = threadIdx.x;
  const int bm = blockIdx.x * 128, bn = blockIdx.y * 128;
  const int w = tid >> 6, lane = tid & 63;
  const int wm = w >> 1, wn = w & 1;
  const int l16 = lane & 15, lg = lane >> 4;
  f32x4 acc[4][4] = {};
  for (int k0 = 0; k0 < K; k0 += 32) {
#pragma unroll
    for (int rep = 0; rep < 2; ++rep) {
      int ci = tid + rep * 256;
      int row = ci >> 2, cg = ci & 3;
      int ar = bm + row;
      ar = ar < M ? ar : M - 1;
      uint4 av = *(const uint4*)(A + (size_t)ar * K + k0 + cg * 8);
      *(uint4*)&Asu[row * 20 + cg * 4] = av;
      uint4 bv = *(const uint4*)(BT + (size_t)(bn + row) * K + k0 + cg * 8);
      *(uint4*)&Bsu[row * 20 + cg * 4] = bv;
    }
    __syncthreads();
    bf16x8 aF[4], bF[4];
#pragma unroll
    for (int mi = 0; mi < 4; ++mi)
      aF[mi] = *(const bf16x8*)&Asu[(wm * 64 + mi * 16 + l16) * 20 + lg * 4];
#pragma unroll
    for (int ni = 0; ni < 4; ++ni)
      bF[ni] = *(const bf16x8*)&Bsu[(wn * 64 + ni * 16 + l16) * 20 + lg * 4];
#pragma unroll
    for (int mi = 0; mi < 4; ++mi)
#pragma unroll
      for (int ni = 0; ni < 4; ++ni)
        acc[mi][ni] =
            __builtin_amdgcn_mfma_f32_16x16x32_bf16(aF[mi], bF[ni], acc[mi][ni], 0, 0, 0);
    __syncthreads();
  }
  float asv[4], adv[4];
#pragma unroll
  for (int ni = 0; ni < 4; ++ni) {
    int gcol = bn + wn * 64 + ni * 16 + l16;
    asv[ni] = as_[gcol];
    adv[ni] = ad_[gcol];
  }
  const int hb = (bn >> 5) + wn * 2;  // even head base
#pragma unroll
  for (int mi = 0; mi < 4; ++mi) {
#pragma unroll
    for (int r = 0; r < 4; ++r) {
      int grow = bm + wm * 64 + mi * 16 + lg * 4 + r;
      bool ok = grow < M;
      if (ok) {
#pragma unroll
        for (int ni = 0; ni < 4; ++ni) {
          int gcol = bn + wn * 64 + ni * 16 + l16;
          C[(size_t)grow * Nn + gcol] = f2b(acc[mi][ni][r]);
        }
      }
      float ps0 = acc[mi][0][r] * asv[0] + acc[mi][1][r] * asv[1];
      float ps1 = acc[mi][2][r] * asv[2] + acc[mi][3][r] * asv[3];
      float pd0 = acc[mi][0][r] * adv[0] + acc[mi][1][r] * adv[1];
      float pd1 = acc[mi][2][r] * adv[2] + acc[mi][3][r] * adv[3];
#pragma unroll
      for (int off = 1; off < 16; off <<= 1) {
        ps0 += __shfl_xor(ps0, off);
        ps1 += __shfl_xor(ps1, off);
        pd0 += __shfl_xor(pd0, off);
        pd1 += __shfl_xor(pd1, off);
      }
      if (ok && l16 == 0) {
        *(float2*)(als + (size_t)grow * 8 + hb) = make_float2(ps0, ps1);
        *(float2*)(ald + (size_t)grow * 8 + hb) = make_float2(pd0, pd1);
      }
    }
  }
}

// ---------------- GAT aggregation: quarter-wave per edge, software-pipelined (R9 best) ----------------
__global__ __launch_bounds__(256) void k_agg(const unsigned short* __restrict__ h,
                                             const float* __restrict__ als,
                                             const float* __restrict__ ald,
                                             const int* __restrict__ ptr,
                                             const int* __restrict__ srcs,
                                             const float* __restrict__ bias,
                                             unsigned short* __restrict__ out, int n) {
  int wid = (blockIdx.x * 256 + threadIdx.x) >> 6;
  int lane = threadIdx.x & 63;
  if (wid >= n) return;
  const int beg = ptr[wid], end = ptr[wid + 1];
  const int L = lane & 15;   // channel slot: channels 16L..16L+15
  const int e = lane >> 4;   // edge slot 0..3
  const int hh = L >> 1;     // head of my 16 channels
  const float adh = ald[(size_t)wid * 8 + hh];
  float s = 0.f;
  float a0 = 0, a1 = 0, a2 = 0, a3 = 0, a4 = 0, a5 = 0, a6 = 0, a7 = 0;
  float a8 = 0, a9 = 0, aA = 0, aB = 0, aC = 0, aD = 0, aE = 0, aF = 0;
  int j = beg + e;
  int s0 = j < end ? srcs[j] : 0;
  int s1 = (j + 4) < end ? srcs[j + 4] : 0;
  const uint4* hp0 = (const uint4*)(h + (size_t)s0 * 256 + L * 16);
  uint4 c0 = hp0[0];
  uint4 c1 = hp0[1];
  float alsc = als[(size_t)s0 * 8 + hh];
  for (; j < end; j += 4) {
    int s2 = (j + 8) < end ? srcs[j + 8] : 0;
    const uint4* hp1 = (const uint4*)(h + (size_t)s1 * 256 + L * 16);
    uint4 n0 = hp1[0];
    uint4 n1 = hp1[1];
    float alsn = als[(size_t)s1 * 8 + hh];
    float lg = lrelu(alsc + adh, 0.2f);
    float wt = __expf(lg);  // m == 0: logits are O(1), no overflow possible
    s += wt;
    a0 += wt * b2f_lo(c0.x); a1 += wt * b2f_hi(c0.x);
    a2 += wt * b2f_lo(c0.y); a3 += wt * b2f_hi(c0.y);
    a4 += wt * b2f_lo(c0.z); a5 += wt * b2f_hi(c0.z);
    a6 += wt * b2f_lo(c0.w); a7 += wt * b2f_hi(c0.w);
    a8 += wt * b2f_lo(c1.x); a9 += wt * b2f_hi(c1.x);
    aA += wt * b2f_lo(c1.y); aB += wt * b2f_hi(c1.y);
    aC += wt * b2f_lo(c1.z); aD += wt * b2f_hi(c1.z);
    aE += wt * b2f_lo(c1.w); aF += wt * b2f_hi(c1.w);
    c0 = n0; c1 = n1; alsc = alsn;
    s1 = s2;
  }
  a0 += __shfl_xor(a0, 16); a0 += __shfl_xor(a0, 32);
  a1 += __shfl_xor(a1, 16); a1 += __shfl_xor(a1, 32);
  a2 += __shfl_xor(a2, 16); a2 += __shfl_xor(a2, 32);
  a3 += __shfl_xor(a3, 16); a3 += __shfl_xor(a3, 32);
  a4 += __shfl_xor(a4, 16); a4 += __shfl_xor(a4, 32);
  a5 += __shfl_xor(a5, 16); a5 += __shfl_xor(a5, 32);
  a6 += __shfl_xor(a6, 16); a6 += __shfl_xor(a6, 32);
  a7 += __shfl_xor(a7, 16); a7 += __shfl_xor(a7, 32);
  a8 += __shfl_xor(a8, 16); a8 += __shfl_xor(a8, 32);
  a9 += __shfl_xor(a9, 16); a9 += __shfl_xor(a9, 32);
  aA += __shfl_xor(aA, 16); aA += __shfl_xor(aA, 32);
  aB += __shfl_xor(aB, 16); aB += __shfl_xor(aB, 32);
  aC += __shfl_xor(aC, 16); aC += __shfl_xor(aC, 32);
  aD += __shfl_xor(aD, 16); aD += __shfl_xor(aD, 32);
  aE += __shfl_xor(aE, 16); aE += __shfl_xor(aE, 32);
  aF += __shfl_xor(aF, 16); aF += __shfl_xor(aF, 32);
  s += __shfl_xor(s, 16); s += __shfl_xor(s, 32);
  const float inv = 1.f / (s + 1e-16f);
  if (e == 0) {
    const float4* bp = (const float4*)(bias + L * 16);
    float4 b0 = bp[0], b1 = bp[1], b2 = bp[2], b3 = bp[3];
    uint4 o0, o1;
    o0.x = (unsigned int)f2b(a0 * inv + b0.x) | ((unsigned int)f2b(a1 * inv + b0.y) << 16);
    o0.y = (unsigned int)f2b(a2 * inv + b0.z) | ((unsigned int)f2b(a3 * inv + b0.w) << 16);
    o0.z = (unsigned int)f2b(a4 * inv + b1.x) | ((unsigned int)f2b(a5 * inv + b1.y) << 16);
    o0.w = (unsigned int)f2b(a6 * inv + b1.z) | ((unsigned int)f2b(a7 * inv + b1.w) << 16);
    o1.x = (unsigned int)f2b(a8 * inv + b2.x) | ((unsigned int)f2b(a9 * inv + b2.y) << 16);
    o1.y = (unsigned int)f2b(aA * inv + b2.z) | ((unsigned int)f2b(aB * inv + b2.w) << 16);
    o1.z = (unsigned int)f2b(aC * inv + b3.x) | ((unsigned int)f2b(aD * inv + b3.y) << 16);
    o1.w = (unsigned int)f2b(aE * inv + b3.z) | ((unsigned int)f2b(aF * inv + b3.w) << 16);
    uint4* op = (uint4*)(out + (size_t)wid * 256 + L * 16);
    op[0] = o0;
    op[1] = o1;
  }
}

// ---------------- fused BN stack (layer 1): bnp1 -> bnp2 -> bnact, grid 512 ----------------
__global__ __launch_bounds__(256, 2) void k_bn1(int* __restrict__ bar,
                                                const unsigned short* __restrict__ xa,
                                                float* __restrict__ partial,
                                                const float* __restrict__ ga,
                                                const float* __restrict__ be,
                                                float* __restrict__ ss, float invn,
                                                unsigned short* __restrict__ outb, int n) {
  const int NB = gridDim.x;  // 512
  const int t = threadIdx.x;
  {  // bnp1
    const int q = t & 63;
    const int rsub = t >> 6;
    float s0 = 0, s1 = 0, s2 = 0, s3 = 0, q0 = 0, q1 = 0, q2 = 0, q3 = 0;
    int r = blockIdx.x * 4 + rsub;
    for (; r + 6144 < n; r += 8192) {
      ushort4 va = *(const ushort4*)(xa + (size_t)r * 256 + q * 4);
      ushort4 vb = *(const ushort4*)(xa + (size_t)(r + 2048) * 256 + q * 4);
      ushort4 vc = *(const ushort4*)(xa + (size_t)(r + 4096) * 256 + q * 4);
      ushort4 vd = *(const ushort4*)(xa + (size_t)(r + 6144) * 256 + q * 4);
      float f;
      f = b2f(va.x); s0 += f; q0 += f * f;
      f = b2f(va.y); s1 += f; q1 += f * f;
      f = b2f(va.z); s2 += f; q2 += f * f;
      f = b2f(va.w); s3 += f; q3 += f * f;
      f = b2f(vb.x); s0 += f; q0 += f * f;
      f = b2f(vb.y); s1 += f; q1 += f * f;
      f = b2f(vb.z); s2 += f; q2 += f * f;
      f = b2f(vb.w); s3 += f; q3 += f * f;
      f = b2f(vc.x); s0 += f; q0 += f * f;
      f = b2f(vc.y); s1 += f; q1 += f * f;
      f = b2f(vc.z); s2 += f; q2 += f * f;
      f = b2f(vc.w); s3 += f; q3 += f * f;
      f = b2f(vd.x); s0 += f; q0 += f * f;
      f = b2f(vd.y); s1 += f; q1 += f * f;
      f = b2f(vd.z); s2 += f; q2 += f * f;
      f = b2f(vd.w); s3 += f; q3 += f * f;
    }
    for (; r < n; r += 2048) {
      ushort4 v = *(const ushort4*)(xa + (size_t)r * 256 + q * 4);
      float f;
      f = b2f(v.x); s0 += f; q0 += f * f;
      f = b2f(v.y); s1 += f; q1 += f * f;
      f = b2f(v.z); s2 += f; q2 += f * f;
      f = b2f(v.w); s3 += f; q3 += f * f;
    }
    __shared__ float ls[4][512];
    ls[rsub][q * 4 + 0] = s0; ls[rsub][q * 4 + 1] = s1;
    ls[rsub][q * 4 + 2] = s2; ls[rsub][q * 4 + 3] = s3;
    ls[rsub][256 + q * 4 + 0] = q0; ls[rsub][256 + q * 4 + 1] = q1;
    ls[rsub][256 + q * 4 + 2] = q2; ls[rsub][256 + q * 4 + 3] = q3;
    __syncthreads();
    float a = ls[0][t] + ls[1][t] + ls[2][t] + ls[3][t];
    float b = ls[0][256 + t] + ls[1][256 + t] + ls[2][256 + t] + ls[3][256 + t];
    partial[blockIdx.x * 512 + t] = a;
    partial[blockIdx.x * 512 + 256 + t] = b;
  }
  gbar(bar, NB);
  if (blockIdx.x < 64) {  // bnp2 -> scale/shift
    const int c = blockIdx.x * 4 + (t >> 6);
    const int lane = t & 63;
    float s = 0.f, qq = 0.f;
#pragma unroll
    for (int k = 0; k < 8; ++k) {
      int b = lane + k * 64;
      s += partial[(size_t)b * 512 + c];
      qq += partial[(size_t)b * 512 + 256 + c];
    }
#pragma unroll
    for (int off = 1; off < 64; off <<= 1) {
      s += __shfl_xor(s, off);
      qq += __shfl_xor(qq, off);
    }
    if (lane == 0) {
      float mu = s * invn;
      float var = qq * invn - mu * mu;
      float sc = ga[c] * rsqrtf(var + 1e-5f);
      ss[c] = sc;
      ss[256 + c] = be[c] - mu * sc;
    }
  }
  gbar(bar, NB);
  {  // bnact
    const int tot4 = n * 64;
    for (int i = blockIdx.x * 256 + t; i < tot4; i += NB * 256) {
      int i0 = i * 4;
      int c = i0 & 255;
      ushort4 xu = *(const ushort4*)(xa + i0);
      float4 scv = *(const float4*)(ss + c);
      float4 shv = *(const float4*)(ss + 256 + c);
      float t0 = b2f(xu.x) * scv.x + shv.x;
      float t1 = b2f(xu.y) * scv.y + shv.y;
      float t2 = b2f(xu.z) * scv.z + shv.z;
      float t3 = b2f(xu.w) * scv.w + shv.w;
      float o0 = fmaxf(t0, 0.01f * t0);
      float o1 = fmaxf(t1, 0.01f * t1);
      float o2 = fmaxf(t2, 0.01f * t2);
      float o3 = fmaxf(t3, 0.01f * t3);
      ushort4 ob;
      ob.x = f2b(o0); ob.y = f2b(o1); ob.z = f2b(o2); ob.w = f2b(o3);
      *(ushort4*)(outb + i0) = ob;
    }
  }
}

// ---------------- fused BN stack (layer 2): bnp1 -> bnp2 -> bnact3(+W3 GEMM), grid 512 ----------------
__global__ __launch_bounds__(256, 2) void k_bn2(int* __restrict__ bar,
                                                const unsigned short* __restrict__ xa,
                                                float* __restrict__ partial,
                                                const float* __restrict__ ga,
                                                const float* __restrict__ be,
                                                float* __restrict__ ss, float invn,
                                                const unsigned short* __restrict__ res,
                                                const float* __restrict__ W3,
                                                const float* __restrict__ as3,
                                                const float* __restrict__ ad3,
                                                uint4* __restrict__ h3p, int n) {
  const int NB = gridDim.x;  // 512
  const int t = threadIdx.x;
  {  // bnp1
    const int q = t & 63;
    const int rsub = t >> 6;
    float s0 = 0, s1 = 0, s2 = 0, s3 = 0, q0 = 0, q1 = 0, q2 = 0, q3 = 0;
    int r = blockIdx.x * 4 + rsub;
    for (; r + 6144 < n; r += 8192) {
      ushort4 va = *(const ushort4*)(xa + (size_t)r * 256 + q * 4);
      ushort4 vb = *(const ushort4*)(xa + (size_t)(r + 2048) * 256 + q * 4);
      ushort4 vc = *(const ushort4*)(xa + (size_t)(r + 4096) * 256 + q * 4);
      ushort4 vd = *(const ushort4*)(xa + (size_t)(r + 6144) * 256 + q * 4);
      float f;
      f = b2f(va.x); s0 += f; q0 += f * f;
      f = b2f(va.y); s1 += f; q1 += f * f;
      f = b2f(va.z); s2 += f; q2 += f * f;
      f = b2f(va.w); s3 += f; q3 += f * f;
      f = b2f(vb.x); s0 += f; q0 += f * f;
      f = b2f(vb.y); s1 += f; q1 += f * f;
      f = b2f(vb.z); s2 += f; q2 += f * f;
      f = b2f(vb.w); s3 += f; q3 += f * f;
      f = b2f(vc.x); s0 += f; q0 += f * f;
      f = b2f(vc.y); s1 += f; q1 += f * f;
      f = b2f(vc.z); s2 += f; q2 += f * f;
      f = b2f(vc.w); s3 += f; q3 += f * f;
      f = b2f(vd.x); s0 += f; q0 += f * f;
      f = b2f(vd.y); s1 += f; q1 += f * f;
      f = b2f(vd.z); s2 += f; q2 += f * f;
      f = b2f(vd.w); s3 += f; q3 += f * f;
    }
    for (; r < n; r += 2048) {
      ushort4 v = *(const ushort4*)(xa + (size_t)r * 256 + q * 4);
      float f;
      f = b2f(v.x); s0 += f; q0 += f * f;
      f = b2f(v.y); s1 += f; q1 += f * f;
      f = b2f(v.z); s2 += f; q2 += f * f;
      f = b2f(v.w); s3 += f; q3 += f * f;
    }
    __shared__ float ls[4][512];
    ls[rsub][q * 4 + 0] = s0; ls[rsub][q * 4 + 1] = s1;
    ls[rsub][q * 4 + 2] = s2; ls[rsub][q * 4 + 3] = s3;
    ls[rsub][256 + q * 4 + 0] = q0; ls[rsub][256 + q * 4 + 1] = q1;
    ls[rsub][256 + q * 4 + 2] = q2; ls[rsub][256 + q * 4 + 3] = q3;
    __syncthreads();
    float a = ls[0][t] + ls[1][t] + ls[2][t] + ls[3][t];
    float b = ls[0][256 + t] + ls[1][256 + t] + ls[2][256 + t] + ls[3][256 + t];
    partial[blockIdx.x * 512 + t] = a;
    partial[blockIdx.x * 512 + 256 + t] = b;
  }
  gbar(bar, NB);
  if (blockIdx.x < 64) {  // bnp2
    const int c = blockIdx.x * 4 + (t >> 6);
    const int lane = t & 63;
    float s = 0.f, qq = 0.f;
#pragma unroll
    for (int k = 0; k < 8; ++k) {
      int b = lane + k * 64;
      s += partial[(size_t)b * 512 + c];
      qq += partial[(size_t)b * 512 + 256 + c];
    }
#pragma unroll
    for (int off = 1; off < 64; off <<= 1) {
      s += __shfl_xor(s, off);
      qq += __shfl_xor(qq, off);
    }
    if (lane == 0) {
      float mu = s * invn;
      float var = qq * invn - mu * mu;
      float sc = ga[c] * rsqrtf(var + 1e-5f);
      ss[c] = sc;
      ss[256 + c] = be[c] - mu * sc;
    }
  }
  gbar(bar, NB);
  {  // bnact3: wave per node, grid-stride
    const int lane = t & 63;
    const int c = lane * 4;
    const float4* Wp = (const float4*)W3 + lane * 4;
    float4 w0 = Wp[0], w1 = Wp[1], w2 = Wp[2], w3 = Wp[3];
    float4 scv = *(const float4*)(ss + c);
    float4 shv = *(const float4*)(ss + 256 + c);
    for (int wid = blockIdx.x * 4 + (t >> 6); wid < n; wid += NB * 4) {
      ushort4 xu = *(const ushort4*)(xa + (size_t)wid * 256 + c);
      ushort4 rv = *(const ushort4*)(res + (size_t)wid * 256 + c);
      float t0 = b2f(xu.x) * scv.x + shv.x;
      float t1 = b2f(xu.y) * scv.y + shv.y;
      float t2 = b2f(xu.z) * scv.z + shv.z;
      float t3 = b2f(xu.w) * scv.w + shv.w;
      float o0 = fmaxf(t0, 0.01f * t0) + b2f(rv.x);
      float o1 = fmaxf(t1, 0.01f * t1) + b2f(rv.y);
      float o2 = fmaxf(t2, 0.01f * t2) + b2f(rv.z);
      float o3 = fmaxf(t3, 0.01f * t3) + b2f(rv.w);
      float a0 = o0 * w0.x + o1 * w1.x + o2 * w2.x + o3 * w3.x;
      float a1 = o0 * w0.y + o1 * w1.y + o2 * w2.y + o3 * w3.y;
      float a2 = o0 * w0.z + o1 * w1.z + o2 * w2.z + o3 * w3.z;
      float a3 = o0 * w0.w + o1 * w1.w + o2 * w2.w + o3 * w3.w;
#pragma unroll
      for (int off = 1; off < 64; off <<= 1) {
        a0 += __shfl_xor(a0, off);
        a1 += __shfl_xor(a1, off);
        a2 += __shfl_xor(a2, off);
        a3 += __shfl_xor(a3, off);
      }
      if (lane == 0) {
        float als3v = a0 * as3[0] + a1 * as3[1] + a2 * as3[2] + a3 * as3[3];
        float ald3v = a0 * ad3[0] + a1 * ad3[1] + a2 * ad3[2] + a3 * ad3[3];
        uint4 pv;
        pv.x = (unsigned int)f2b(a0) | ((unsigned int)f2b(a1) << 16);
        pv.y = (unsigned int)f2b(a2) | ((unsigned int)f2b(a3) << 16);
        pv.z = fbits(als3v);
        pv.w = fbits(ald3v);
        h3p[wid] = pv;
      }
    }
  }
}

// ---------------- layer 3 aggregation: single 16B load per edge -> d_out ----------------
__global__ __launch_bounds__(256) void k_agg3(const uint4* __restrict__ h3p,
                                              const int* __restrict__ ptr,
                                              const int* __restrict__ srcs,
                                              const float* __restrict__ b3,
                                              float* __restrict__ out, int n) {
  int wid = (blockIdx.x * 256 + threadIdx.x) >> 6;
  int lane = threadIdx.x & 63;
  if (wid >= n) return;
  const int beg = ptr[wid], end = ptr[wid + 1];
  const float aldh = bitsf(h3p[wid].w);
  float s = 0.f, a0 = 0.f, a1 = 0.f, a2 = 0.f, a3 = 0.f;
  for (int j = beg + lane; j < end; j += 64) {
    uint4 v = h3p[srcs[j]];
    float wgt = __expf(lrelu(bitsf(v.z) + aldh, 0.2f));  // m == 0
    s += wgt;
    a0 += wgt * b2f_lo(v.x);
    a1 += wgt * b2f_hi(v.x);
    a2 += wgt * b2f_lo(v.y);
    a3 += wgt * b2f_hi(v.y);
  }
#pragma unroll
  for (int off = 1; off < 64; off <<= 1) {
    s += __shfl_xor(s, off);
    a0 += __shfl_xor(a0, off);
    a1 += __shfl_xor(a1, off);
    a2 += __shfl_xor(a2, off);
    a3 += __shfl_xor(a3, off);
  }
  if (lane == 0) {
    float inv = 1.f / (s + 1e-16f);
    out[(size_t)wid * 4 + 0] = a0 * inv + b3[0];
    out[(size_t)wid * 4 + 1] = a1 * inv + b3[1];
    out[(size_t)wid * 4 + 2] = a2 * inv + b3[2];
    out[(size_t)wid * 4 + 3] = a3 * inv + b3[3];
  }
}

extern "C" void kernel_launch(void* const* d_in, const int* in_sizes, int n_in,
                              void* d_out, int out_size, void* d_ws, size_t ws_size,
                              hipStream_t stream) {
  const float* x   = (const float*)d_in[0];
  const int*   ei  = (const int*)d_in[1];
  const float* W1  = (const float*)d_in[2];
  const float* as1 = (const float*)d_in[3];
  const float* ad1 = (const float*)d_in[4];
  const float* b1  = (const float*)d_in[5];
  const float* ga1 = (const float*)d_in[6];
  const float* be1 = (const float*)d_in[7];
  const float* W2  = (const float*)d_in[8];
  const float* as2 = (const float*)d_in[9];
  const float* ad2 = (const float*)d_in[10];
  const float* b2  = (const float*)d_in[11];
  const float* ga2 = (const float*)d_in[12];
  const float* be2 = (const float*)d_in[13];
  const float* W3  = (const float*)d_in[14];
  const float* as3 = (const float*)d_in[15];
  const float* ad3 = (const float*)d_in[16];
  const float* b3  = (const float*)d_in[17];

  const int N = in_sizes[0] / 128;
  const int E = in_sizes[1] / 2;
  const int ET = E + N;
  float* out = (float*)d_out;

  char* w = (char*)d_ws;
  auto alloc = [&](size_t bytes) -> void* {
    void* p = (void*)w;
    w += (bytes + 255) & ~(size_t)255;
    return p;
  };
  int* bar              = (int*)alloc(6 * 4);  // 3 {count,sense} pairs
  int* ptr              = (int*)alloc((size_t)(N + 1) * 4);
  int* fill             = (int*)alloc((size_t)N * 4);
  int* cnt              = (int*)alloc((size_t)N * 4);
  int* bsum             = (int*)alloc(64 * 4);
  int* srcs             = (int*)alloc((size_t)ET * 4);
  unsigned short* hbuf  = (unsigned short*)alloc((size_t)N * 256 * 2);
  unsigned short* aggb  = (unsigned short*)alloc((size_t)N * 256 * 2);
  unsigned short* a1b   = (unsigned short*)alloc((size_t)N * 256 * 2);
  unsigned short* xb    = (unsigned short*)alloc((size_t)N * 128 * 2);
  unsigned short* w1t   = (unsigned short*)alloc(256 * 128 * 2);
  unsigned short* w2t   = (unsigned short*)alloc(256 * 256 * 2);
  float* als            = (float*)alloc((size_t)N * 8 * 4);
  float* ald            = (float*)alloc((size_t)N * 8 * 4);
  uint4* h3p            = (uint4*)alloc((size_t)N * 16);
  float* partial        = (float*)alloc(512 * 512 * 4);
  float* ss             = (float*)alloc(1024 * 4);  // [sc1|sh1 | sc2|sh2]

  const int* esrc = ei;
  const int* edst = ei + E;
  const float invn = 1.f / (float)N;

  hipMemsetAsync(bar, 0, 6 * 4, stream);  // arm grid barriers (d_ws may be poisoned)

  // fused CSR build + bf16 prep (one dispatch)
  k_csr<<<512, 256, 0, stream>>>(bar, cnt, esrc, edst, E, N, x, xb, W1, w1t, W2, w2t,
                                 bsum, ptr, fill, srcs);

  const dim3 gemm_grid((N + 127) / 128, 2);
  const int wblocks = (N + 3) / 4;

  // layer 1
  k_mfma<<<gemm_grid, 256, 0, stream>>>(xb, w1t, hbuf, as1, ad1, als, ald, N, 256, 128);
  k_agg<<<wblocks, 256, 0, stream>>>(hbuf, als, ald, ptr, srcs, b1, aggb, N);
  k_bn1<<<512, 256, 0, stream>>>(bar + 2, aggb, partial, ga1, be1, ss, invn, a1b, N);

  // layer 2 (+ residual a1b)
  k_mfma<<<gemm_grid, 256, 0, stream>>>(a1b, w2t, hbuf, as2, ad2, als, ald, N, 256, 256);
  k_agg<<<wblocks, 256, 0, stream>>>(hbuf, als, ald, ptr, srcs, b2, aggb, N);
  k_bn2<<<512, 256, 0, stream>>>(bar + 4, aggb, partial, ga2, be2, ss + 512, invn,
                                 a1b, W3, as3, ad3, h3p, N);

  // layer 3 aggregation -> output
  k_agg3<<<wblocks, 256, 0, stream>>>(h3p, ptr, srcs, b3, out, N);
}

// Round 13
// 613.703 us; speedup vs baseline: 1.7109x; 1.7109x over previous
//
#include <hip/hip_runtime.h>

typedef __attribute__((ext_vector_type(8))) short bf16x8;
typedef __attribute__((ext_vector_type(4))) float f32x4;

__device__ __forceinline__ float lrelu(float x, float s) { return x >= 0.f ? x : s * x; }
__device__ __forceinline__ float b2f(unsigned short u) {
  union { unsigned int i; float f; } v; v.i = ((unsigned int)u) << 16; return v.f;
}
__device__ __forceinline__ float b2f_lo(unsigned int u) {
  union { unsigned int i; float f; } v; v.i = u << 16; return v.f;
}
__device__ __forceinline__ float b2f_hi(unsigned int u) {
  union { unsigned int i; float f; } v; v.i = u & 0xffff0000u; return v.f;
}
__device__ __forceinline__ unsigned short f2b(float f) {
  union { float f; unsigned int i; } v; v.f = f;
  unsigned int r = v.i + 0x7fffu + ((v.i >> 16) & 1u);
  return (unsigned short)(r >> 16);
}
__device__ __forceinline__ unsigned int fbits(float f) {
  union { float f; unsigned int i; } v; v.f = f; return v.i;
}
__device__ __forceinline__ float bitsf(unsigned int u) {
  union { unsigned int i; float f; } v; v.i = u; return v.f;
}

// ---------------- CSR build. cnt holds in-degree only; +1 self-loop folded into scan ----------------
__global__ __launch_bounds__(256) void k_hist(const int* __restrict__ dst, int e,
                                              int* __restrict__ cnt) {
  int i = blockIdx.x * 256 + threadIdx.x;
  if (i < e) atomicAdd(&cnt[dst[i]], 1);
}

__global__ __launch_bounds__(256) void k_bsum(const int* __restrict__ cnt,
                                              int* __restrict__ bsum, int n) {
  const int base = blockIdx.x * 1024;
  const int t = threadIdx.x;
  int s = 0;
#pragma unroll
  for (int i = 0; i < 4; ++i) {
    int idx = base + t + i * 256;
    if (idx < n) s += cnt[idx] + 1;  // +1 = self-loop
  }
#pragma unroll
  for (int off = 1; off < 64; off <<= 1) s += __shfl_xor(s, off);
  __shared__ int ws[4];
  const int lane = t & 63, w = t >> 6;
  if (lane == 0) ws[w] = s;
  __syncthreads();
  if (t == 0) bsum[blockIdx.x] = ws[0] + ws[1] + ws[2] + ws[3];
}

// local scan; each block redundantly wave-scans bsum (B<=64) for its global offset
__global__ __launch_bounds__(256) void k_scanl(const int* __restrict__ cnt,
                                               const int* __restrict__ bsum,
                                               int* __restrict__ ptr,
                                               int* __restrict__ fill, int n, int B) {
  __shared__ int ws[4];
  __shared__ int bo;
  const int t = threadIdx.x;
  if (t < 64) {
    int v = t < B ? bsum[t] : 0;
    int incl = v;
#pragma unroll
    for (int off = 1; off < 64; off <<= 1) {
      int u = __shfl_up(incl, off);
      if (t >= off) incl += u;
    }
    if (t == blockIdx.x) bo = incl - v;
    if (blockIdx.x == 0 && t == 63) ptr[n] = incl;
  }
  const int base = blockIdx.x * 1024 + t * 4;
  int v0 = base + 0 < n ? cnt[base + 0] + 1 : 0;
  int v1 = base + 1 < n ? cnt[base + 1] + 1 : 0;
  int v2 = base + 2 < n ? cnt[base + 2] + 1 : 0;
  int v3 = base + 3 < n ? cnt[base + 3] + 1 : 0;
  const int tsum = v0 + v1 + v2 + v3;
  const int lane = t & 63, w = t >> 6;
  int incl = tsum;
#pragma unroll
  for (int off = 1; off < 64; off <<= 1) {
    int u = __shfl_up(incl, off);
    if (lane >= off) incl += u;
  }
  if (lane == 63) ws[w] = incl;
  __syncthreads();
  int excl = bo + incl - tsum;
  for (int i = 0; i < w; ++i) excl += ws[i];
  if (base + 0 < n) { ptr[base + 0] = excl; fill[base + 0] = excl; }
  excl += v0;
  if (base + 1 < n) { ptr[base + 1] = excl; fill[base + 1] = excl; }
  excl += v1;
  if (base + 2 < n) { ptr[base + 2] = excl; fill[base + 2] = excl; }
  excl += v2;
  if (base + 3 < n) { ptr[base + 3] = excl; fill[base + 3] = excl; }
}

__global__ __launch_bounds__(256) void k_scatter(const int* __restrict__ srce,
                                                 const int* __restrict__ dste,
                                                 int e, int n,
                                                 int* __restrict__ fill,
                                                 int* __restrict__ srcs) {
  int i = blockIdx.x * 256 + threadIdx.x;
  if (i < e) {
    int pos = atomicAdd(&fill[dste[i]], 1);
    __builtin_nontemporal_store(srce[i], &srcs[pos]);
  } else if (i < e + n) {
    int v = i - e;
    int pos = atomicAdd(&fill[v], 1);
    __builtin_nontemporal_store(v, &srcs[pos]);
  }
}

// ---------------- combined: zero cnt + x->bf16 + W1->W1T + W2->W2T ----------------
__global__ __launch_bounds__(256) void k_prep(int* __restrict__ cnt, int n,
                                              const float* __restrict__ x,
                                              unsigned short* __restrict__ xb,
                                              const float* __restrict__ W1,
                                              unsigned short* __restrict__ w1t,
                                              const float* __restrict__ W2,
                                              unsigned short* __restrict__ w2t, int n4) {
  int i = blockIdx.x * 256 + threadIdx.x;
  if (i < n) {
    cnt[i] = 0;
    return;
  }
  i -= n;
  if (i < n4) {
    float4 v = ((const float4*)x)[i];
    ushort4 o;
    o.x = f2b(v.x); o.y = f2b(v.y); o.z = f2b(v.z); o.w = f2b(v.w);
    ((ushort4*)xb)[i] = o;
    return;
  }
  i -= n4;
  if (i < 256 * 128) {
    int nn = i >> 7, k = i & 127;
    w1t[i] = f2b(W1[(size_t)k * 256 + nn]);
    return;
  }
  i -= 256 * 128;
  if (i < 256 * 256) {
    int nn = i >> 8, k = i & 255;
    w2t[i] = f2b(W2[(size_t)k * 256 + nn]);
  }
}

// ---------------- bf16 MFMA GEMM + fused attention coefficients ----------------
__global__ __launch_bounds__(256) void k_mfma(const unsigned short* __restrict__ A,
                                              const unsigned short* __restrict__ BT,
                                              unsigned short* __restrict__ C,
                                              const float* __restrict__ as_,
                                              const float* __restrict__ ad_,
                                              float* __restrict__ als,
                                              float* __restrict__ ald,
                                              int M, int Nn, int K) {
  __shared__ unsigned int Asu[128 * 20];
  __shared__ unsigned int Bsu[128 * 20];
  const int tid = threadIdx.x;
  const int bm = blockIdx.x * 128, bn = blockIdx.y * 128;
  const int w = tid >> 6, lane = tid & 63;
  const int wm = w >> 1, wn = w & 1;
  const int l16 = lane & 15, lg = lane >> 4;
  f32x4 acc[4][4] = {};
  for (int k0 = 0; k0 < K; k0 += 32) {
#pragma unroll
    for (int rep = 0; rep < 2; ++rep) {
      int ci = tid + rep * 256;
      int row = ci >> 2, cg = ci & 3;
      int ar = bm + row;
      ar = ar < M ? ar : M - 1;
      uint4 av = *(const uint4*)(A + (size_t)ar * K + k0 + cg * 8);
      *(uint4*)&Asu[row * 20 + cg * 4] = av;
      uint4 bv = *(const uint4*)(BT + (size_t)(bn + row) * K + k0 + cg * 8);
      *(uint4*)&Bsu[row * 20 + cg * 4] = bv;
    }
    __syncthreads();
    bf16x8 aF[4], bF[4];
#pragma unroll
    for (int mi = 0; mi < 4; ++mi)
      aF[mi] = *(const bf16x8*)&Asu[(wm * 64 + mi * 16 + l16) * 20 + lg * 4];
#pragma unroll
    for (int ni = 0; ni < 4; ++ni)
      bF[ni] = *(const bf16x8*)&Bsu[(wn * 64 + ni * 16 + l16) * 20 + lg * 4];
#pragma unroll
    for (int mi = 0; mi < 4; ++mi)
#pragma unroll
      for (int ni = 0; ni < 4; ++ni)
        acc[mi][ni] =
            __builtin_amdgcn_mfma_f32_16x16x32_bf16(aF[mi], bF[ni], acc[mi][ni], 0, 0, 0);
    __syncthreads();
  }
  float asv[4], adv[4];
#pragma unroll
  for (int ni = 0; ni < 4; ++ni) {
    int gcol = bn + wn * 64 + ni * 16 + l16;
    asv[ni] = as_[gcol];
    adv[ni] = ad_[gcol];
  }
  const int hb = (bn >> 5) + wn * 2;  // even head base
#pragma unroll
  for (int mi = 0; mi < 4; ++mi) {
#pragma unroll
    for (int r = 0; r < 4; ++r) {
      int grow = bm + wm * 64 + mi * 16 + lg * 4 + r;
      bool ok = grow < M;
      if (ok) {
#pragma unroll
        for (int ni = 0; ni < 4; ++ni) {
          int gcol = bn + wn * 64 + ni * 16 + l16;
          C[(size_t)grow * Nn + gcol] = f2b(acc[mi][ni][r]);
        }
      }
      float ps0 = acc[mi][0][r] * asv[0] + acc[mi][1][r] * asv[1];
      float ps1 = acc[mi][2][r] * asv[2] + acc[mi][3][r] * asv[3];
      float pd0 = acc[mi][0][r] * adv[0] + acc[mi][1][r] * adv[1];
      float pd1 = acc[mi][2][r] * adv[2] + acc[mi][3][r] * adv[3];
#pragma unroll
      for (int off = 1; off < 16; off <<= 1) {
        ps0 += __shfl_xor(ps0, off);
        ps1 += __shfl_xor(ps1, off);
        pd0 += __shfl_xor(pd0, off);
        pd1 += __shfl_xor(pd1, off);
      }
      if (ok && l16 == 0) {
        *(float2*)(als + (size_t)grow * 8 + hb) = make_float2(ps0, ps1);
        *(float2*)(ald + (size_t)grow * 8 + hb) = make_float2(pd0, pd1);
      }
    }
  }
}

// ---------------- GAT aggregation: head-sliced for per-XCD L2 locality ----------------
// head = blockIdx & 7 (dispatch round-robins blocks over the 8 XCDs, so each head's
// 64B/row slice (3.2 MB) stays resident in ONE XCD's 4 MB L2). One wave per (dst, head):
// 16 edge slots x 4 channel-lanes (16B/lane).
__global__ __launch_bounds__(256) void k_agg(const unsigned short* __restrict__ h,
                                             const float* __restrict__ als,
                                             const float* __restrict__ ald,
                                             const int* __restrict__ ptr,
                                             const int* __restrict__ srcs,
                                             const float* __restrict__ bias,
                                             unsigned short* __restrict__ out, int n) {
  const int head = blockIdx.x & 7;
  const int wv = threadIdx.x >> 6;
  const int lane = threadIdx.x & 63;
  const int e = lane >> 2;   // edge slot 0..15
  const int l = lane & 3;    // channel lane 0..3 (8 bf16 each)
  const int ch = head * 32 + l * 8;
  const float4 bv0 = *(const float4*)(bias + ch);
  const float4 bv1 = *(const float4*)(bias + ch + 4);
  const int dst0 = (blockIdx.x >> 3) * 4 + wv;
  const int dstep = (gridDim.x >> 3) * 4;
  for (int dst = dst0; dst < n; dst += dstep) {
    const int beg = ptr[dst], end = ptr[dst + 1];
    const float adh = ald[(size_t)dst * 8 + head];
    float s = 0.f;
    float a0 = 0, a1 = 0, a2 = 0, a3 = 0, a4 = 0, a5 = 0, a6 = 0, a7 = 0;
    for (int j = beg + e; j < end; j += 16) {
      int src = __builtin_nontemporal_load(&srcs[j]);
      float wt = __expf(lrelu(als[(size_t)src * 8 + head] + adh, 0.2f));  // m == 0
      uint4 hv = *(const uint4*)(h + (size_t)src * 256 + ch);
      s += wt;
      a0 += wt * b2f_lo(hv.x); a1 += wt * b2f_hi(hv.x);
      a2 += wt * b2f_lo(hv.y); a3 += wt * b2f_hi(hv.y);
      a4 += wt * b2f_lo(hv.z); a5 += wt * b2f_hi(hv.z);
      a6 += wt * b2f_lo(hv.w); a7 += wt * b2f_hi(hv.w);
    }
    // reduce across edge-slot bits (2..5); channel bits (0..1) untouched
#pragma unroll
    for (int off = 4; off < 64; off <<= 1) {
      s  += __shfl_xor(s, off);
      a0 += __shfl_xor(a0, off);
      a1 += __shfl_xor(a1, off);
      a2 += __shfl_xor(a2, off);
      a3 += __shfl_xor(a3, off);
      a4 += __shfl_xor(a4, off);
      a5 += __shfl_xor(a5, off);
      a6 += __shfl_xor(a6, off);
      a7 += __shfl_xor(a7, off);
    }
    if (e == 0) {
      float inv = 1.f / (s + 1e-16f);
      uint4 o;
      o.x = (unsigned int)f2b(a0 * inv + bv0.x) | ((unsigned int)f2b(a1 * inv + bv0.y) << 16);
      o.y = (unsigned int)f2b(a2 * inv + bv0.z) | ((unsigned int)f2b(a3 * inv + bv0.w) << 16);
      o.z = (unsigned int)f2b(a4 * inv + bv1.x) | ((unsigned int)f2b(a5 * inv + bv1.y) << 16);
      o.w = (unsigned int)f2b(a6 * inv + bv1.z) | ((unsigned int)f2b(a7 * inv + bv1.w) << 16);
      *(uint4*)(out + (size_t)dst * 256 + ch) = o;
    }
  }
}

// ---------------- BN stats pass 1: 512 blocks, 4 independent row loads in flight ----------------
__global__ __launch_bounds__(256) void k_bnp1(const unsigned short* __restrict__ x,
                                              float* __restrict__ partial, int n) {
  const int t = threadIdx.x;
  const int q = t & 63;
  const int rsub = t >> 6;
  float s0 = 0, s1 = 0, s2 = 0, s3 = 0, q0 = 0, q1 = 0, q2 = 0, q3 = 0;
  int r = blockIdx.x * 4 + rsub;
  for (; r + 6144 < n; r += 8192) {
    ushort4 va = *(const ushort4*)(x + (size_t)r * 256 + q * 4);
    ushort4 vb = *(const ushort4*)(x + (size_t)(r + 2048) * 256 + q * 4);
    ushort4 vc = *(const ushort4*)(x + (size_t)(r + 4096) * 256 + q * 4);
    ushort4 vd = *(const ushort4*)(x + (size_t)(r + 6144) * 256 + q * 4);
    float f;
    f = b2f(va.x); s0 += f; q0 += f * f;
    f = b2f(va.y); s1 += f; q1 += f * f;
    f = b2f(va.z); s2 += f; q2 += f * f;
    f = b2f(va.w); s3 += f; q3 += f * f;
    f = b2f(vb.x); s0 += f; q0 += f * f;
    f = b2f(vb.y); s1 += f; q1 += f * f;
    f = b2f(vb.z); s2 += f; q2 += f * f;
    f = b2f(vb.w); s3 += f; q3 += f * f;
    f = b2f(vc.x); s0 += f; q0 += f * f;
    f = b2f(vc.y); s1 += f; q1 += f * f;
    f = b2f(vc.z); s2 += f; q2 += f * f;
    f = b2f(vc.w); s3 += f; q3 += f * f;
    f = b2f(vd.x); s0 += f; q0 += f * f;
    f = b2f(vd.y); s1 += f; q1 += f * f;
    f = b2f(vd.z); s2 += f; q2 += f * f;
    f = b2f(vd.w); s3 += f; q3 += f * f;
  }
  for (; r < n; r += 2048) {
    ushort4 v = *(const ushort4*)(x + (size_t)r * 256 + q * 4);
    float f;
    f = b2f(v.x); s0 += f; q0 += f * f;
    f = b2f(v.y); s1 += f; q1 += f * f;
    f = b2f(v.z); s2 += f; q2 += f * f;
    f = b2f(v.w); s3 += f; q3 += f * f;
  }
  __shared__ float ls[4][512];
  ls[rsub][q * 4 + 0] = s0; ls[rsub][q * 4 + 1] = s1;
  ls[rsub][q * 4 + 2] = s2; ls[rsub][q * 4 + 3] = s3;
  ls[rsub][256 + q * 4 + 0] = q0; ls[rsub][256 + q * 4 + 1] = q1;
  ls[rsub][256 + q * 4 + 2] = q2; ls[rsub][256 + q * 4 + 3] = q3;
  __syncthreads();
  float a = ls[0][t] + ls[1][t] + ls[2][t] + ls[3][t];
  float b = ls[0][256 + t] + ls[1][256 + t] + ls[2][256 + t] + ls[3][256 + t];
  partial[blockIdx.x * 512 + t] = a;
  partial[blockIdx.x * 512 + 256 + t] = b;
}

// ---------------- BN stats pass 2: wave per channel; outputs scale/shift ----------------
__global__ __launch_bounds__(256) void k_bnp2(const float* __restrict__ partial,
                                              const float* __restrict__ ga,
                                              const float* __restrict__ be,
                                              float* __restrict__ ss, float invn) {
  const int c = blockIdx.x * 4 + (threadIdx.x >> 6);
  const int lane = threadIdx.x & 63;
  float s = 0.f, qq = 0.f;
#pragma unroll
  for (int k = 0; k < 8; ++k) {
    int b = lane + k * 64;
    s += partial[(size_t)b * 512 + c];
    qq += partial[(size_t)b * 512 + 256 + c];
  }
#pragma unroll
  for (int off = 1; off < 64; off <<= 1) {
    s += __shfl_xor(s, off);
    qq += __shfl_xor(qq, off);
  }
  if (lane == 0) {
    float mu = s * invn;
    float var = qq * invn - mu * mu;
    float sc = ga[c] * rsqrtf(var + 1e-5f);
    ss[c] = sc;
    ss[256 + c] = be[c] - mu * sc;
  }
}

// ---------------- fused BN apply + LeakyReLU -> bf16 (layer 1), scale/shift form ----------------
__global__ __launch_bounds__(256) void k_bnact(const unsigned short* __restrict__ x,
                                               const float* __restrict__ ss,
                                               unsigned short* __restrict__ out, int n) {
  const int tot4 = n * 64;
  for (int t = blockIdx.x * 256 + threadIdx.x; t < tot4; t += gridDim.x * 256) {
    int i0 = t * 4;
    int c = i0 & 255;
    ushort4 xu = *(const ushort4*)(x + i0);
    float4 scv = *(const float4*)(ss + c);
    float4 shv = *(const float4*)(ss + 256 + c);
    float t0 = b2f(xu.x) * scv.x + shv.x;
    float t1 = b2f(xu.y) * scv.y + shv.y;
    float t2 = b2f(xu.z) * scv.z + shv.z;
    float t3 = b2f(xu.w) * scv.w + shv.w;
    float o0 = fmaxf(t0, 0.01f * t0);
    float o1 = fmaxf(t1, 0.01f * t1);
    float o2 = fmaxf(t2, 0.01f * t2);
    float o3 = fmaxf(t3, 0.01f * t3);
    ushort4 ob;
    ob.x = f2b(o0); ob.y = f2b(o1); ob.z = f2b(o2); ob.w = f2b(o3);
    *(ushort4*)(out + i0) = ob;
  }
}

// ---------------- layer2 BN+LReLU+residual fused with layer3 GEMM (wave per node) ----------------
__global__ __launch_bounds__(256) void k_bnact3(const unsigned short* __restrict__ x,
                                                const float* __restrict__ ss,
                                                const unsigned short* __restrict__ res,
                                                const float* __restrict__ W3,
                                                const float* __restrict__ as3,
                                                const float* __restrict__ ad3,
                                                uint4* __restrict__ h3p, int n) {
  int wid = (blockIdx.x * 256 + threadIdx.x) >> 6;
  int lane = threadIdx.x & 63;
  if (wid >= n) return;
  const int c = lane * 4;
  ushort4 xu = *(const ushort4*)(x + (size_t)wid * 256 + c);
  ushort4 rv = *(const ushort4*)(res + (size_t)wid * 256 + c);
  float4 scv = *(const float4*)(ss + c);
  float4 shv = *(const float4*)(ss + 256 + c);
  float t0 = b2f(xu.x) * scv.x + shv.x;
  float t1 = b2f(xu.y) * scv.y + shv.y;
  float t2 = b2f(xu.z) * scv.z + shv.z;
  float t3 = b2f(xu.w) * scv.w + shv.w;
  float o0 = fmaxf(t0, 0.01f * t0) + b2f(rv.x);
  float o1 = fmaxf(t1, 0.01f * t1) + b2f(rv.y);
  float o2 = fmaxf(t2, 0.01f * t2) + b2f(rv.z);
  float o3 = fmaxf(t3, 0.01f * t3) + b2f(rv.w);
  const float4* Wp = (const float4*)W3 + lane * 4;
  float4 w0 = Wp[0], w1 = Wp[1], w2 = Wp[2], w3 = Wp[3];
  float a0 = o0 * w0.x + o1 * w1.x + o2 * w2.x + o3 * w3.x;
  float a1 = o0 * w0.y + o1 * w1.y + o2 * w2.y + o3 * w3.y;
  float a2 = o0 * w0.z + o1 * w1.z + o2 * w2.z + o3 * w3.z;
  float a3 = o0 * w0.w + o1 * w1.w + o2 * w2.w + o3 * w3.w;
#pragma unroll
  for (int off = 1; off < 64; off <<= 1) {
    a0 += __shfl_xor(a0, off);
    a1 += __shfl_xor(a1, off);
    a2 += __shfl_xor(a2, off);
    a3 += __shfl_xor(a3, off);
  }
  if (lane == 0) {
    float als3v = a0 * as3[0] + a1 * as3[1] + a2 * as3[2] + a3 * as3[3];
    float ald3v = a0 * ad3[0] + a1 * ad3[1] + a2 * ad3[2] + a3 * ad3[3];
    uint4 pv;
    pv.x = (unsigned int)f2b(a0) | ((unsigned int)f2b(a1) << 16);
    pv.y = (unsigned int)f2b(a2) | ((unsigned int)f2b(a3) << 16);
    pv.z = fbits(als3v);
    pv.w = fbits(ald3v);
    h3p[wid] = pv;
  }
}

// ---------------- layer 3 aggregation: single 16B load per edge -> d_out ----------------
__global__ __launch_bounds__(256) void k_agg3(const uint4* __restrict__ h3p,
                                              const int* __restrict__ ptr,
                                              const int* __restrict__ srcs,
                                              const float* __restrict__ b3,
                                              float* __restrict__ out, int n) {
  int wid = (blockIdx.x * 256 + threadIdx.x) >> 6;
  int lane = threadIdx.x & 63;
  if (wid >= n) return;
  const int beg = ptr[wid], end = ptr[wid + 1];
  const float aldh = bitsf(h3p[wid].w);
  float s = 0.f, a0 = 0.f, a1 = 0.f, a2 = 0.f, a3 = 0.f;
  for (int j = beg + lane; j < end; j += 64) {
    uint4 v = h3p[srcs[j]];
    float wgt = __expf(lrelu(bitsf(v.z) + aldh, 0.2f));  // m == 0
    s += wgt;
    a0 += wgt * b2f_lo(v.x);
    a1 += wgt * b2f_hi(v.x);
    a2 += wgt * b2f_lo(v.y);
    a3 += wgt * b2f_hi(v.y);
  }
#pragma unroll
  for (int off = 1; off < 64; off <<= 1) {
    s += __shfl_xor(s, off);
    a0 += __shfl_xor(a0, off);
    a1 += __shfl_xor(a1, off);
    a2 += __shfl_xor(a2, off);
    a3 += __shfl_xor(a3, off);
  }
  if (lane == 0) {
    float inv = 1.f / (s + 1e-16f);
    out[(size_t)wid * 4 + 0] = a0 * inv + b3[0];
    out[(size_t)wid * 4 + 1] = a1 * inv + b3[1];
    out[(size_t)wid * 4 + 2] = a2 * inv + b3[2];
    out[(size_t)wid * 4 + 3] = a3 * inv + b3[3];
  }
}

extern "C" void kernel_launch(void* const* d_in, const int* in_sizes, int n_in,
                              void* d_out, int out_size, void* d_ws, size_t ws_size,
                              hipStream_t stream) {
  const float* x   = (const float*)d_in[0];
  const int*   ei  = (const int*)d_in[1];
  const float* W1  = (const float*)d_in[2];
  const float* as1 = (const float*)d_in[3];
  const float* ad1 = (const float*)d_in[4];
  const float* b1  = (const float*)d_in[5];
  const float* ga1 = (const float*)d_in[6];
  const float* be1 = (const float*)d_in[7];
  const float* W2  = (const float*)d_in[8];
  const float* as2 = (const float*)d_in[9];
  const float* ad2 = (const float*)d_in[10];
  const float* b2  = (const float*)d_in[11];
  const float* ga2 = (const float*)d_in[12];
  const float* be2 = (const float*)d_in[13];
  const float* W3  = (const float*)d_in[14];
  const float* as3 = (const float*)d_in[15];
  const float* ad3 = (const float*)d_in[16];
  const float* b3  = (const float*)d_in[17];

  const int N = in_sizes[0] / 128;
  const int E = in_sizes[1] / 2;
  const int ET = E + N;
  float* out = (float*)d_out;

  char* w = (char*)d_ws;
  auto alloc = [&](size_t bytes) -> void* {
    void* p = (void*)w;
    w += (bytes + 255) & ~(size_t)255;
    return p;
  };
  int* ptr              = (int*)alloc((size_t)(N + 1) * 4);
  int* fill             = (int*)alloc((size_t)N * 4);
  int* cnt              = (int*)alloc((size_t)N * 4);
  int* bsum             = (int*)alloc(64 * 4);
  int* srcs             = (int*)alloc((size_t)ET * 4);
  unsigned short* hbuf  = (unsigned short*)alloc((size_t)N * 256 * 2);
  unsigned short* aggb  = (unsigned short*)alloc((size_t)N * 256 * 2);
  unsigned short* a1b   = (unsigned short*)alloc((size_t)N * 256 * 2);
  unsigned short* xb    = (unsigned short*)alloc((size_t)N * 128 * 2);
  unsigned short* w1t   = (unsigned short*)alloc(256 * 128 * 2);
  unsigned short* w2t   = (unsigned short*)alloc(256 * 256 * 2);
  float* als            = (float*)alloc((size_t)N * 8 * 4);
  float* ald            = (float*)alloc((size_t)N * 8 * 4);
  uint4* h3p            = (uint4*)alloc((size_t)N * 16);
  float* partial        = (float*)alloc(512 * 512 * 4);
  float* ss             = (float*)alloc(1024 * 4);  // [sc1|sh1 | sc2|sh2]

  const int* esrc = ei;
  const int* edst = ei + E;
  const float invn = 1.f / (float)N;

  // prep: zero cnt + all bf16 conversions (one launch)
  const int n4 = N * 32;
  const int prep_tot = N + n4 + 256 * 128 + 256 * 256;
  k_prep<<<(prep_tot + 255) / 256, 256, 0, stream>>>(cnt, N, x, xb, W1, w1t, W2, w2t, n4);

  // CSR (shared by all three layers)
  const int B = (N + 1023) / 1024;  // must be <= 64
  k_hist<<<(E + 255) / 256, 256, 0, stream>>>(edst, E, cnt);
  k_bsum<<<B, 256, 0, stream>>>(cnt, bsum, N);
  k_scanl<<<B, 256, 0, stream>>>(cnt, bsum, ptr, fill, N, B);
  k_scatter<<<(ET + 255) / 256, 256, 0, stream>>>(esrc, edst, E, N, fill, srcs);

  const dim3 gemm_grid((N + 127) / 128, 2);
  const int wblocks = (N + 3) / 4;
  const int agg_grid = 2048;  // multiple of 8: head = blockIdx & 7 -> XCD pinning

  // layer 1
  k_mfma<<<gemm_grid, 256, 0, stream>>>(xb, w1t, hbuf, as1, ad1, als, ald, N, 256, 128);
  k_agg<<<agg_grid, 256, 0, stream>>>(hbuf, als, ald, ptr, srcs, b1, aggb, N);
  k_bnp1<<<512, 256, 0, stream>>>(aggb, partial, N);
  k_bnp2<<<64, 256, 0, stream>>>(partial, ga1, be1, ss, invn);
  k_bnact<<<2048, 256, 0, stream>>>(aggb, ss, a1b, N);

  // layer 2 (+ residual a1b)
  k_mfma<<<gemm_grid, 256, 0, stream>>>(a1b, w2t, hbuf, as2, ad2, als, ald, N, 256, 256);
  k_agg<<<agg_grid, 256, 0, stream>>>(hbuf, als, ald, ptr, srcs, b2, aggb, N);
  k_bnp1<<<512, 256, 0, stream>>>(aggb, partial, N);
  k_bnp2<<<64, 256, 0, stream>>>(partial, ga2, be2, ss + 512, invn);
  k_bnact3<<<wblocks, 256, 0, stream>>>(aggb, ss + 512, a1b, W3, as3, ad3, h3p, N);

  // layer 3 aggregation -> output
  k_agg3<<<wblocks, 256, 0, stream>>>(h3p, ptr, srcs, b3, out, N);
}

// Round 14
// 365.115 us; speedup vs baseline: 2.8758x; 1.6808x over previous
//
#include <hip/hip_runtime.h>

typedef __attribute__((ext_vector_type(8))) short bf16x8;
typedef __attribute__((ext_vector_type(4))) float f32x4;

__device__ __forceinline__ float lrelu(float x, float s) { return x >= 0.f ? x : s * x; }
__device__ __forceinline__ float b2f(unsigned short u) {
  union { unsigned int i; float f; } v; v.i = ((unsigned int)u) << 16; return v.f;
}
__device__ __forceinline__ float b2f_lo(unsigned int u) {
  union { unsigned int i; float f; } v; v.i = u << 16; return v.f;
}
__device__ __forceinline__ float b2f_hi(unsigned int u) {
  union { unsigned int i; float f; } v; v.i = u & 0xffff0000u; return v.f;
}
__device__ __forceinline__ unsigned short f2b(float f) {
  union { float f; unsigned int i; } v; v.f = f;
  unsigned int r = v.i + 0x7fffu + ((v.i >> 16) & 1u);
  return (unsigned short)(r >> 16);
}
__device__ __forceinline__ unsigned int fbits(float f) {
  union { float f; unsigned int i; } v; v.f = f; return v.i;
}
__device__ __forceinline__ float bitsf(unsigned int u) {
  union { unsigned int i; float f; } v; v.i = u; return v.f;
}

// ---------------- CSR build. cnt holds in-degree only; +1 self-loop folded into scan ----------------
__global__ __launch_bounds__(256) void k_hist(const int* __restrict__ dst, int e,
                                              int* __restrict__ cnt) {
  int i = blockIdx.x * 256 + threadIdx.x;
  if (i < e) atomicAdd(&cnt[dst[i]], 1);
}

__global__ __launch_bounds__(256) void k_bsum(const int* __restrict__ cnt,
                                              int* __restrict__ bsum, int n) {
  const int base = blockIdx.x * 1024;
  const int t = threadIdx.x;
  int s = 0;
#pragma unroll
  for (int i = 0; i < 4; ++i) {
    int idx = base + t + i * 256;
    if (idx < n) s += cnt[idx] + 1;  // +1 = self-loop
  }
#pragma unroll
  for (int off = 1; off < 64; off <<= 1) s += __shfl_xor(s, off);
  __shared__ int ws[4];
  const int lane = t & 63, w = t >> 6;
  if (lane == 0) ws[w] = s;
  __syncthreads();
  if (t == 0) bsum[blockIdx.x] = ws[0] + ws[1] + ws[2] + ws[3];
}

// local scan; each block redundantly wave-scans bsum (B<=64) for its global offset
__global__ __launch_bounds__(256) void k_scanl(const int* __restrict__ cnt,
                                               const int* __restrict__ bsum,
                                               int* __restrict__ ptr,
                                               int* __restrict__ fill, int n, int B) {
  __shared__ int ws[4];
  __shared__ int bo;
  const int t = threadIdx.x;
  if (t < 64) {
    int v = t < B ? bsum[t] : 0;
    int incl = v;
#pragma unroll
    for (int off = 1; off < 64; off <<= 1) {
      int u = __shfl_up(incl, off);
      if (t >= off) incl += u;
    }
    if (t == blockIdx.x) bo = incl - v;
    if (blockIdx.x == 0 && t == 63) ptr[n] = incl;
  }
  const int base = blockIdx.x * 1024 + t * 4;
  int v0 = base + 0 < n ? cnt[base + 0] + 1 : 0;
  int v1 = base + 1 < n ? cnt[base + 1] + 1 : 0;
  int v2 = base + 2 < n ? cnt[base + 2] + 1 : 0;
  int v3 = base + 3 < n ? cnt[base + 3] + 1 : 0;
  const int tsum = v0 + v1 + v2 + v3;
  const int lane = t & 63, w = t >> 6;
  int incl = tsum;
#pragma unroll
  for (int off = 1; off < 64; off <<= 1) {
    int u = __shfl_up(incl, off);
    if (lane >= off) incl += u;
  }
  if (lane == 63) ws[w] = incl;
  __syncthreads();
  int excl = bo + incl - tsum;
  for (int i = 0; i < w; ++i) excl += ws[i];
  if (base + 0 < n) { ptr[base + 0] = excl; fill[base + 0] = excl; }
  excl += v0;
  if (base + 1 < n) { ptr[base + 1] = excl; fill[base + 1] = excl; }
  excl += v1;
  if (base + 2 < n) { ptr[base + 2] = excl; fill[base + 2] = excl; }
  excl += v2;
  if (base + 3 < n) { ptr[base + 3] = excl; fill[base + 3] = excl; }
}

__global__ __launch_bounds__(256) void k_scatter(const int* __restrict__ srce,
                                                 const int* __restrict__ dste,
                                                 int e, int n,
                                                 int* __restrict__ fill,
                                                 int* __restrict__ srcs) {
  int i = blockIdx.x * 256 + threadIdx.x;
  if (i < e) {
    int pos = atomicAdd(&fill[dste[i]], 1);
    __builtin_nontemporal_store(srce[i], &srcs[pos]);
  } else if (i < e + n) {
    int v = i - e;
    int pos = atomicAdd(&fill[v], 1);
    __builtin_nontemporal_store(v, &srcs[pos]);
  }
}

// ---------------- combined: zero cnt + x->bf16 + W1->W1T + W2->W2T ----------------
__global__ __launch_bounds__(256) void k_prep(int* __restrict__ cnt, int n,
                                              const float* __restrict__ x,
                                              unsigned short* __restrict__ xb,
                                              const float* __restrict__ W1,
                                              unsigned short* __restrict__ w1t,
                                              const float* __restrict__ W2,
                                              unsigned short* __restrict__ w2t, int n4) {
  int i = blockIdx.x * 256 + threadIdx.x;
  if (i < n) {
    cnt[i] = 0;
    return;
  }
  i -= n;
  if (i < n4) {
    float4 v = ((const float4*)x)[i];
    ushort4 o;
    o.x = f2b(v.x); o.y = f2b(v.y); o.z = f2b(v.z); o.w = f2b(v.w);
    ((ushort4*)xb)[i] = o;
    return;
  }
  i -= n4;
  if (i < 256 * 128) {
    int nn = i >> 7, k = i & 127;
    w1t[i] = f2b(W1[(size_t)k * 256 + nn]);
    return;
  }
  i -= 256 * 128;
  if (i < 256 * 256) {
    int nn = i >> 8, k = i & 255;
    w2t[i] = f2b(W2[(size_t)k * 256 + nn]);
  }
}

// ---------------- bf16 MFMA GEMM + fused attention coefficients ----------------
__global__ __launch_bounds__(256) void k_mfma(const unsigned short* __restrict__ A,
                                              const unsigned short* __restrict__ BT,
                                              unsigned short* __restrict__ C,
                                              const float* __restrict__ as_,
                                              const float* __restrict__ ad_,
                                              float* __restrict__ als,
                                              float* __restrict__ ald,
                                              int M, int Nn, int K) {
  __shared__ unsigned int Asu[128 * 20];
  __shared__ unsigned int Bsu[128 * 20];
  const int tid = threadIdx.x;
  const int bm = blockIdx.x * 128, bn = blockIdx.y * 128;
  const int w = tid >> 6, lane = tid & 63;
  const int wm = w >> 1, wn = w & 1;
  const int l16 = lane & 15, lg = lane >> 4;
  f32x4 acc[4][4] = {};
  for (int k0 = 0; k0 < K; k0 += 32) {
#pragma unroll
    for (int rep = 0; rep < 2; ++rep) {
      int ci = tid + rep * 256;
      int row = ci >> 2, cg = ci & 3;
      int ar = bm + row;
      ar = ar < M ? ar : M - 1;
      uint4 av = *(const uint4*)(A + (size_t)ar * K + k0 + cg * 8);
      *(uint4*)&Asu[row * 20 + cg * 4] = av;
      uint4 bv = *(const uint4*)(BT + (size_t)(bn + row) * K + k0 + cg * 8);
      *(uint4*)&Bsu[row * 20 + cg * 4] = bv;
    }
    __syncthreads();
    bf16x8 aF[4], bF[4];
#pragma unroll
    for (int mi = 0; mi < 4; ++mi)
      aF[mi] = *(const bf16x8*)&Asu[(wm * 64 + mi * 16 + l16) * 20 + lg * 4];
#pragma unroll
    for (int ni = 0; ni < 4; ++ni)
      bF[ni] = *(const bf16x8*)&Bsu[(wn * 64 + ni * 16 + l16) * 20 + lg * 4];
#pragma unroll
    for (int mi = 0; mi < 4; ++mi)
#pragma unroll
      for (int ni = 0; ni < 4; ++ni)
        acc[mi][ni] =
            __builtin_amdgcn_mfma_f32_16x16x32_bf16(aF[mi], bF[ni], acc[mi][ni], 0, 0, 0);
    __syncthreads();
  }
  float asv[4], adv[4];
#pragma unroll
  for (int ni = 0; ni < 4; ++ni) {
    int gcol = bn + wn * 64 + ni * 16 + l16;
    asv[ni] = as_[gcol];
    adv[ni] = ad_[gcol];
  }
  const int hb = (bn >> 5) + wn * 2;  // even head base
#pragma unroll
  for (int mi = 0; mi < 4; ++mi) {
#pragma unroll
    for (int r = 0; r < 4; ++r) {
      int grow = bm + wm * 64 + mi * 16 + lg * 4 + r;
      bool ok = grow < M;
      if (ok) {
#pragma unroll
        for (int ni = 0; ni < 4; ++ni) {
          int gcol = bn + wn * 64 + ni * 16 + l16;
          C[(size_t)grow * Nn + gcol] = f2b(acc[mi][ni][r]);
        }
      }
      float ps0 = acc[mi][0][r] * asv[0] + acc[mi][1][r] * asv[1];
      float ps1 = acc[mi][2][r] * asv[2] + acc[mi][3][r] * asv[3];
      float pd0 = acc[mi][0][r] * adv[0] + acc[mi][1][r] * adv[1];
      float pd1 = acc[mi][2][r] * adv[2] + acc[mi][3][r] * adv[3];
#pragma unroll
      for (int off = 1; off < 16; off <<= 1) {
        ps0 += __shfl_xor(ps0, off);
        ps1 += __shfl_xor(ps1, off);
        pd0 += __shfl_xor(pd0, off);
        pd1 += __shfl_xor(pd1, off);
      }
      if (ok && l16 == 0) {
        *(float2*)(als + (size_t)grow * 8 + hb) = make_float2(ps0, ps1);
        *(float2*)(ald + (size_t)grow * 8 + hb) = make_float2(pd0, pd1);
      }
    }
  }
}

// ---------------- GAT aggregation: quarter-wave per edge, software-pipelined (best: R9/R10) ----------------
__global__ __launch_bounds__(256) void k_agg(const unsigned short* __restrict__ h,
                                             const float* __restrict__ als,
                                             const float* __restrict__ ald,
                                             const int* __restrict__ ptr,
                                             const int* __restrict__ srcs,
                                             const float* __restrict__ bias,
                                             unsigned short* __restrict__ out, int n) {
  int wid = (blockIdx.x * 256 + threadIdx.x) >> 6;
  int lane = threadIdx.x & 63;
  if (wid >= n) return;
  const int beg = ptr[wid], end = ptr[wid + 1];
  const int L = lane & 15;   // channel slot: channels 16L..16L+15
  const int e = lane >> 4;   // edge slot 0..3
  const int hh = L >> 1;     // head of my 16 channels
  const float adh = ald[(size_t)wid * 8 + hh];
  float s = 0.f;
  float a0 = 0, a1 = 0, a2 = 0, a3 = 0, a4 = 0, a5 = 0, a6 = 0, a7 = 0;
  float a8 = 0, a9 = 0, aA = 0, aB = 0, aC = 0, aD = 0, aE = 0, aF = 0;
  int j = beg + e;
  int s0 = j < end ? srcs[j] : 0;
  int s1 = (j + 4) < end ? srcs[j + 4] : 0;
  const uint4* hp0 = (const uint4*)(h + (size_t)s0 * 256 + L * 16);
  uint4 c0 = hp0[0];
  uint4 c1 = hp0[1];
  float alsc = als[(size_t)s0 * 8 + hh];
  for (; j < end; j += 4) {
    int s2 = (j + 8) < end ? srcs[j + 8] : 0;
    const uint4* hp1 = (const uint4*)(h + (size_t)s1 * 256 + L * 16);
    uint4 n0 = hp1[0];
    uint4 n1 = hp1[1];
    float alsn = als[(size_t)s1 * 8 + hh];
    float lg = lrelu(alsc + adh, 0.2f);
    float wt = __expf(lg);  // m == 0: logits are O(1), no overflow possible
    s += wt;
    a0 += wt * b2f_lo(c0.x); a1 += wt * b2f_hi(c0.x);
    a2 += wt * b2f_lo(c0.y); a3 += wt * b2f_hi(c0.y);
    a4 += wt * b2f_lo(c0.z); a5 += wt * b2f_hi(c0.z);
    a6 += wt * b2f_lo(c0.w); a7 += wt * b2f_hi(c0.w);
    a8 += wt * b2f_lo(c1.x); a9 += wt * b2f_hi(c1.x);
    aA += wt * b2f_lo(c1.y); aB += wt * b2f_hi(c1.y);
    aC += wt * b2f_lo(c1.z); aD += wt * b2f_hi(c1.z);
    aE += wt * b2f_lo(c1.w); aF += wt * b2f_hi(c1.w);
    c0 = n0; c1 = n1; alsc = alsn;
    s1 = s2;
  }
  a0 += __shfl_xor(a0, 16); a0 += __shfl_xor(a0, 32);
  a1 += __shfl_xor(a1, 16); a1 += __shfl_xor(a1, 32);
  a2 += __shfl_xor(a2, 16); a2 += __shfl_xor(a2, 32);
  a3 += __shfl_xor(a3, 16); a3 += __shfl_xor(a3, 32);
  a4 += __shfl_xor(a4, 16); a4 += __shfl_xor(a4, 32);
  a5 += __shfl_xor(a5, 16); a5 += __shfl_xor(a5, 32);
  a6 += __shfl_xor(a6, 16); a6 += __shfl_xor(a6, 32);
  a7 += __shfl_xor(a7, 16); a7 += __shfl_xor(a7, 32);
  a8 += __shfl_xor(a8, 16); a8 += __shfl_xor(a8, 32);
  a9 += __shfl_xor(a9, 16); a9 += __shfl_xor(a9, 32);
  aA += __shfl_xor(aA, 16); aA += __shfl_xor(aA, 32);
  aB += __shfl_xor(aB, 16); aB += __shfl_xor(aB, 32);
  aC += __shfl_xor(aC, 16); aC += __shfl_xor(aC, 32);
  aD += __shfl_xor(aD, 16); aD += __shfl_xor(aD, 32);
  aE += __shfl_xor(aE, 16); aE += __shfl_xor(aE, 32);
  aF += __shfl_xor(aF, 16); aF += __shfl_xor(aF, 32);
  s += __shfl_xor(s, 16); s += __shfl_xor(s, 32);
  const float inv = 1.f / (s + 1e-16f);
  if (e == 0) {
    const float4* bp = (const float4*)(bias + L * 16);
    float4 b0 = bp[0], b1 = bp[1], b2 = bp[2], b3 = bp[3];
    uint4 o0, o1;
    o0.x = (unsigned int)f2b(a0 * inv + b0.x) | ((unsigned int)f2b(a1 * inv + b0.y) << 16);
    o0.y = (unsigned int)f2b(a2 * inv + b0.z) | ((unsigned int)f2b(a3 * inv + b0.w) << 16);
    o0.z = (unsigned int)f2b(a4 * inv + b1.x) | ((unsigned int)f2b(a5 * inv + b1.y) << 16);
    o0.w = (unsigned int)f2b(a6 * inv + b1.z) | ((unsigned int)f2b(a7 * inv + b1.w) << 16);
    o1.x = (unsigned int)f2b(a8 * inv + b2.x) | ((unsigned int)f2b(a9 * inv + b2.y) << 16);
    o1.y = (unsigned int)f2b(aA * inv + b2.z) | ((unsigned int)f2b(aB * inv + b2.w) << 16);
    o1.z = (unsigned int)f2b(aC * inv + b3.x) | ((unsigned int)f2b(aD * inv + b3.y) << 16);
    o1.w = (unsigned int)f2b(aE * inv + b3.z) | ((unsigned int)f2b(aF * inv + b3.w) << 16);
    uint4* op = (uint4*)(out + (size_t)wid * 256 + L * 16);
    op[0] = o0;
    op[1] = o1;
  }
}

// ---------------- BN stats pass 1: 512 blocks, 4 independent row loads in flight ----------------
__global__ __launch_bounds__(256) void k_bnp1(const unsigned short* __restrict__ x,
                                              float* __restrict__ partial, int n) {
  const int t = threadIdx.x;
  const int q = t & 63;
  const int rsub = t >> 6;
  float s0 = 0, s1 = 0, s2 = 0, s3 = 0, q0 = 0, q1 = 0, q2 = 0, q3 = 0;
  int r = blockIdx.x * 4 + rsub;
  for (; r + 6144 < n; r += 8192) {
    ushort4 va = *(const ushort4*)(x + (size_t)r * 256 + q * 4);
    ushort4 vb = *(const ushort4*)(x + (size_t)(r + 2048) * 256 + q * 4);
    ushort4 vc = *(const ushort4*)(x + (size_t)(r + 4096) * 256 + q * 4);
    ushort4 vd = *(const ushort4*)(x + (size_t)(r + 6144) * 256 + q * 4);
    float f;
    f = b2f(va.x); s0 += f; q0 += f * f;
    f = b2f(va.y); s1 += f; q1 += f * f;
    f = b2f(va.z); s2 += f; q2 += f * f;
    f = b2f(va.w); s3 += f; q3 += f * f;
    f = b2f(vb.x); s0 += f; q0 += f * f;
    f = b2f(vb.y); s1 += f; q1 += f * f;
    f = b2f(vb.z); s2 += f; q2 += f * f;
    f = b2f(vb.w); s3 += f; q3 += f * f;
    f = b2f(vc.x); s0 += f; q0 += f * f;
    f = b2f(vc.y); s1 += f; q1 += f * f;
    f = b2f(vc.z); s2 += f; q2 += f * f;
    f = b2f(vc.w); s3 += f; q3 += f * f;
    f = b2f(vd.x); s0 += f; q0 += f * f;
    f = b2f(vd.y); s1 += f; q1 += f * f;
    f = b2f(vd.z); s2 += f; q2 += f * f;
    f = b2f(vd.w); s3 += f; q3 += f * f;
  }
  for (; r < n; r += 2048) {
    ushort4 v = *(const ushort4*)(x + (size_t)r * 256 + q * 4);
    float f;
    f = b2f(v.x); s0 += f; q0 += f * f;
    f = b2f(v.y); s1 += f; q1 += f * f;
    f = b2f(v.z); s2 += f; q2 += f * f;
    f = b2f(v.w); s3 += f; q3 += f * f;
  }
  __shared__ float ls[4][512];
  ls[rsub][q * 4 + 0] = s0; ls[rsub][q * 4 + 1] = s1;
  ls[rsub][q * 4 + 2] = s2; ls[rsub][q * 4 + 3] = s3;
  ls[rsub][256 + q * 4 + 0] = q0; ls[rsub][256 + q * 4 + 1] = q1;
  ls[rsub][256 + q * 4 + 2] = q2; ls[rsub][256 + q * 4 + 3] = q3;
  __syncthreads();
  float a = ls[0][t] + ls[1][t] + ls[2][t] + ls[3][t];
  float b = ls[0][256 + t] + ls[1][256 + t] + ls[2][256 + t] + ls[3][256 + t];
  partial[blockIdx.x * 512 + t] = a;
  partial[blockIdx.x * 512 + 256 + t] = b;
}

// ---------------- BN stats pass 2: wave per channel; outputs scale/shift ----------------
__global__ __launch_bounds__(256) void k_bnp2(const float* __restrict__ partial,
                                              const float* __restrict__ ga,
                                              const float* __restrict__ be,
                                              float* __restrict__ ss, float invn) {
  const int c = blockIdx.x * 4 + (threadIdx.x >> 6);
  const int lane = threadIdx.x & 63;
  float s = 0.f, qq = 0.f;
#pragma unroll
  for (int k = 0; k < 8; ++k) {
    int b = lane + k * 64;
    s += partial[(size_t)b * 512 + c];
    qq += partial[(size_t)b * 512 + 256 + c];
  }
#pragma unroll
  for (int off = 1; off < 64; off <<= 1) {
    s += __shfl_xor(s, off);
    qq += __shfl_xor(qq, off);
  }
  if (lane == 0) {
    float mu = s * invn;
    float var = qq * invn - mu * mu;
    float sc = ga[c] * rsqrtf(var + 1e-5f);
    ss[c] = sc;
    ss[256 + c] = be[c] - mu * sc;
  }
}

// ---------------- fused BN apply + LeakyReLU -> bf16 (layer 1), scale/shift form ----------------
__global__ __launch_bounds__(256) void k_bnact(const unsigned short* __restrict__ x,
                                               const float* __restrict__ ss,
                                               unsigned short* __restrict__ out, int n) {
  const int tot4 = n * 64;
  for (int t = blockIdx.x * 256 + threadIdx.x; t < tot4; t += gridDim.x * 256) {
    int i0 = t * 4;
    int c = i0 & 255;
    ushort4 xu = *(const ushort4*)(x + i0);
    float4 scv = *(const float4*)(ss + c);
    float4 shv = *(const float4*)(ss + 256 + c);
    float t0 = b2f(xu.x) * scv.x + shv.x;
    float t1 = b2f(xu.y) * scv.y + shv.y;
    float t2 = b2f(xu.z) * scv.z + shv.z;
    float t3 = b2f(xu.w) * scv.w + shv.w;
    float o0 = fmaxf(t0, 0.01f * t0);
    float o1 = fmaxf(t1, 0.01f * t1);
    float o2 = fmaxf(t2, 0.01f * t2);
    float o3 = fmaxf(t3, 0.01f * t3);
    ushort4 ob;
    ob.x = f2b(o0); ob.y = f2b(o1); ob.z = f2b(o2); ob.w = f2b(o3);
    *(ushort4*)(out + i0) = ob;
  }
}

// ---------------- layer2 BN+LReLU+residual fused with layer3 GEMM (wave per node) ----------------
__global__ __launch_bounds__(256) void k_bnact3(const unsigned short* __restrict__ x,
                                                const float* __restrict__ ss,
                                                const unsigned short* __restrict__ res,
                                                const float* __restrict__ W3,
                                                const float* __restrict__ as3,
                                                const float* __restrict__ ad3,
                                                uint4* __restrict__ h3p, int n) {
  int wid = (blockIdx.x * 256 + threadIdx.x) >> 6;
  int lane = threadIdx.x & 63;
  if (wid >= n) return;
  const int c = lane * 4;
  ushort4 xu = *(const ushort4*)(x + (size_t)wid * 256 + c);
  ushort4 rv = *(const ushort4*)(res + (size_t)wid * 256 + c);
  float4 scv = *(const float4*)(ss + c);
  float4 shv = *(const float4*)(ss + 256 + c);
  float t0 = b2f(xu.x) * scv.x + shv.x;
  float t1 = b2f(xu.y) * scv.y + shv.y;
  float t2 = b2f(xu.z) * scv.z + shv.z;
  float t3 = b2f(xu.w) * scv.w + shv.w;
  float o0 = fmaxf(t0, 0.01f * t0) + b2f(rv.x);
  float o1 = fmaxf(t1, 0.01f * t1) + b2f(rv.y);
  float o2 = fmaxf(t2, 0.01f * t2) + b2f(rv.z);
  float o3 = fmaxf(t3, 0.01f * t3) + b2f(rv.w);
  const float4* Wp = (const float4*)W3 + lane * 4;
  float4 w0 = Wp[0], w1 = Wp[1], w2 = Wp[2], w3 = Wp[3];
  float a0 = o0 * w0.x + o1 * w1.x + o2 * w2.x + o3 * w3.x;
  float a1 = o0 * w0.y + o1 * w1.y + o2 * w2.y + o3 * w3.y;
  float a2 = o0 * w0.z + o1 * w1.z + o2 * w2.z + o3 * w3.z;
  float a3 = o0 * w0.w + o1 * w1.w + o2 * w2.w + o3 * w3.w;
#pragma unroll
  for (int off = 1; off < 64; off <<= 1) {
    a0 += __shfl_xor(a0, off);
    a1 += __shfl_xor(a1, off);
    a2 += __shfl_xor(a2, off);
    a3 += __shfl_xor(a3, off);
  }
  if (lane == 0) {
    float als3v = a0 * as3[0] + a1 * as3[1] + a2 * as3[2] + a3 * as3[3];
    float ald3v = a0 * ad3[0] + a1 * ad3[1] + a2 * ad3[2] + a3 * ad3[3];
    uint4 pv;
    pv.x = (unsigned int)f2b(a0) | ((unsigned int)f2b(a1) << 16);
    pv.y = (unsigned int)f2b(a2) | ((unsigned int)f2b(a3) << 16);
    pv.z = fbits(als3v);
    pv.w = fbits(ald3v);
    h3p[wid] = pv;
  }
}

// ---------------- layer 3 aggregation: 16 lanes/node, 4 nodes/wave -> d_out ----------------
__global__ __launch_bounds__(256) void k_agg3(const uint4* __restrict__ h3p,
                                              const int* __restrict__ ptr,
                                              const int* __restrict__ srcs,
                                              const float* __restrict__ b3,
                                              float* __restrict__ out, int n) {
  const int wv = (blockIdx.x * 256 + threadIdx.x) >> 6;
  const int lane = threadIdx.x & 63;
  const int sl = lane & 15;            // edge slot within node
  const int node = wv * 4 + (lane >> 4);
  const bool ok = node < n;
  int beg = 0, end = 0;
  float aldh = 0.f;
  if (ok) {
    beg = ptr[node];
    end = ptr[node + 1];
    aldh = bitsf(h3p[node].w);
  }
  float s = 0.f, a0 = 0.f, a1 = 0.f, a2 = 0.f, a3 = 0.f;
  for (int j = beg + sl; j < end; j += 16) {
    uint4 v = h3p[srcs[j]];
    float wgt = __expf(lrelu(bitsf(v.z) + aldh, 0.2f));  // m == 0
    s += wgt;
    a0 += wgt * b2f_lo(v.x);
    a1 += wgt * b2f_hi(v.x);
    a2 += wgt * b2f_lo(v.y);
    a3 += wgt * b2f_hi(v.y);
  }
  // reduce across edge-slot bits 0..3 (node bits 4..5 untouched)
#pragma unroll
  for (int off = 1; off < 16; off <<= 1) {
    s += __shfl_xor(s, off);
    a0 += __shfl_xor(a0, off);
    a1 += __shfl_xor(a1, off);
    a2 += __shfl_xor(a2, off);
    a3 += __shfl_xor(a3, off);
  }
  if (ok && sl == 0) {
    float inv = 1.f / (s + 1e-16f);
    float4 o;
    o.x = a0 * inv + b3[0];
    o.y = a1 * inv + b3[1];
    o.z = a2 * inv + b3[2];
    o.w = a3 * inv + b3[3];
    *(float4*)(out + (size_t)node * 4) = o;
  }
}

extern "C" void kernel_launch(void* const* d_in, const int* in_sizes, int n_in,
                              void* d_out, int out_size, void* d_ws, size_t ws_size,
                              hipStream_t stream) {
  const float* x   = (const float*)d_in[0];
  const int*   ei  = (const int*)d_in[1];
  const float* W1  = (const float*)d_in[2];
  const float* as1 = (const float*)d_in[3];
  const float* ad1 = (const float*)d_in[4];
  const float* b1  = (const float*)d_in[5];
  const float* ga1 = (const float*)d_in[6];
  const float* be1 = (const float*)d_in[7];
  const float* W2  = (const float*)d_in[8];
  const float* as2 = (const float*)d_in[9];
  const float* ad2 = (const float*)d_in[10];
  const float* b2  = (const float*)d_in[11];
  const float* ga2 = (const float*)d_in[12];
  const float* be2 = (const float*)d_in[13];
  const float* W3  = (const float*)d_in[14];
  const float* as3 = (const float*)d_in[15];
  const float* ad3 = (const float*)d_in[16];
  const float* b3  = (const float*)d_in[17];

  const int N = in_sizes[0] / 128;
  const int E = in_sizes[1] / 2;
  const int ET = E + N;
  float* out = (float*)d_out;

  char* w = (char*)d_ws;
  auto alloc = [&](size_t bytes) -> void* {
    void* p = (void*)w;
    w += (bytes + 255) & ~(size_t)255;
    return p;
  };
  int* ptr              = (int*)alloc((size_t)(N + 1) * 4);
  int* fill             = (int*)alloc((size_t)N * 4);
  int* cnt              = (int*)alloc((size_t)N * 4);
  int* bsum             = (int*)alloc(64 * 4);
  int* srcs             = (int*)alloc((size_t)ET * 4);
  unsigned short* hbuf  = (unsigned short*)alloc((size_t)N * 256 * 2);
  unsigned short* aggb  = (unsigned short*)alloc((size_t)N * 256 * 2);
  unsigned short* a1b   = (unsigned short*)alloc((size_t)N * 256 * 2);
  unsigned short* xb    = (unsigned short*)alloc((size_t)N * 128 * 2);
  unsigned short* w1t   = (unsigned short*)alloc(256 * 128 * 2);
  unsigned short* w2t   = (unsigned short*)alloc(256 * 256 * 2);
  float* als            = (float*)alloc((size_t)N * 8 * 4);
  float* ald            = (float*)alloc((size_t)N * 8 * 4);
  uint4* h3p            = (uint4*)alloc((size_t)N * 16);
  float* partial        = (float*)alloc(512 * 512 * 4);
  float* ss             = (float*)alloc(1024 * 4);  // [sc1|sh1 | sc2|sh2]

  const int* esrc = ei;
  const int* edst = ei + E;
  const float invn = 1.f / (float)N;

  // prep: zero cnt + all bf16 conversions (one launch)
  const int n4 = N * 32;
  const int prep_tot = N + n4 + 256 * 128 + 256 * 256;
  k_prep<<<(prep_tot + 255) / 256, 256, 0, stream>>>(cnt, N, x, xb, W1, w1t, W2, w2t, n4);

  // CSR (shared by all three layers)
  const int B = (N + 1023) / 1024;  // must be <= 64
  k_hist<<<(E + 255) / 256, 256, 0, stream>>>(edst, E, cnt);
  k_bsum<<<B, 256, 0, stream>>>(cnt, bsum, N);
  k_scanl<<<B, 256, 0, stream>>>(cnt, bsum, ptr, fill, N, B);
  k_scatter<<<(ET + 255) / 256, 256, 0, stream>>>(esrc, edst, E, N, fill, srcs);

  const dim3 gemm_grid((N + 127) / 128, 2);
  const int wblocks = (N + 3) / 4;
  const int wblocks4 = (N + 15) / 16;  // k_agg3: 4 nodes per wave

  // layer 1
  k_mfma<<<gemm_grid, 256, 0, stream>>>(xb, w1t, hbuf, as1, ad1, als, ald, N, 256, 128);
  k_agg<<<wblocks, 256, 0, stream>>>(hbuf, als, ald, ptr, srcs, b1, aggb, N);
  k_bnp1<<<512, 256, 0, stream>>>(aggb, partial, N);
  k_bnp2<<<64, 256, 0, stream>>>(partial, ga1, be1, ss, invn);
  k_bnact<<<2048, 256, 0, stream>>>(aggb, ss, a1b, N);

  // layer 2 (+ residual a1b)
  k_mfma<<<gemm_grid, 256, 0, stream>>>(a1b, w2t, hbuf, as2, ad2, als, ald, N, 256, 256);
  k_agg<<<wblocks, 256, 0, stream>>>(hbuf, als, ald, ptr, srcs, b2, aggb, N);
  k_bnp1<<<512, 256, 0, stream>>>(aggb, partial, N);
  k_bnp2<<<64, 256, 0, stream>>>(partial, ga2, be2, ss + 512, invn);
  k_bnact3<<<wblocks, 256, 0, stream>>>(aggb, ss + 512, a1b, W3, as3, ad3, h3p, N);

  // layer 3 aggregation -> output
  k_agg3<<<wblocks4, 256, 0, stream>>>(h3p, ptr, srcs, b3, out, N);
}

// Round 15
// 358.729 us; speedup vs baseline: 2.9270x; 1.0178x over previous
//
#include <hip/hip_runtime.h>

typedef __attribute__((ext_vector_type(8))) short bf16x8;
typedef __attribute__((ext_vector_type(4))) float f32x4;

__device__ __forceinline__ float lrelu(float x, float s) { return x >= 0.f ? x : s * x; }
__device__ __forceinline__ float b2f(unsigned short u) {
  union { unsigned int i; float f; } v; v.i = ((unsigned int)u) << 16; return v.f;
}
__device__ __forceinline__ float b2f_lo(unsigned int u) {
  union { unsigned int i; float f; } v; v.i = u << 16; return v.f;
}
__device__ __forceinline__ float b2f_hi(unsigned int u) {
  union { unsigned int i; float f; } v; v.i = u & 0xffff0000u; return v.f;
}
__device__ __forceinline__ unsigned short f2b(float f) {
  union { float f; unsigned int i; } v; v.f = f;
  unsigned int r = v.i + 0x7fffu + ((v.i >> 16) & 1u);
  return (unsigned short)(r >> 16);
}
__device__ __forceinline__ unsigned int fbits(float f) {
  union { float f; unsigned int i; } v; v.f = f; return v.i;
}
__device__ __forceinline__ float bitsf(unsigned int u) {
  union { unsigned int i; float f; } v; v.i = u; return v.f;
}

// ---------------- CSR build. cnt holds in-degree only; +1 self-loop folded into scan ----------------
__global__ __launch_bounds__(256) void k_hist(const int* __restrict__ dst, int e,
                                              int* __restrict__ cnt) {
  int i = blockIdx.x * 256 + threadIdx.x;
  if (i < e) atomicAdd(&cnt[dst[i]], 1);
}

__global__ __launch_bounds__(256) void k_bsum(const int* __restrict__ cnt,
                                              int* __restrict__ bsum, int n) {
  const int base = blockIdx.x * 1024;
  const int t = threadIdx.x;
  int s = 0;
#pragma unroll
  for (int i = 0; i < 4; ++i) {
    int idx = base + t + i * 256;
    if (idx < n) s += cnt[idx] + 1;  // +1 = self-loop
  }
#pragma unroll
  for (int off = 1; off < 64; off <<= 1) s += __shfl_xor(s, off);
  __shared__ int ws[4];
  const int lane = t & 63, w = t >> 6;
  if (lane == 0) ws[w] = s;
  __syncthreads();
  if (t == 0) bsum[blockIdx.x] = ws[0] + ws[1] + ws[2] + ws[3];
}

// local scan; each block redundantly wave-scans bsum (B<=64) for its global offset
__global__ __launch_bounds__(256) void k_scanl(const int* __restrict__ cnt,
                                               const int* __restrict__ bsum,
                                               int* __restrict__ ptr,
                                               int* __restrict__ fill, int n, int B) {
  __shared__ int ws[4];
  __shared__ int bo;
  const int t = threadIdx.x;
  if (t < 64) {
    int v = t < B ? bsum[t] : 0;
    int incl = v;
#pragma unroll
    for (int off = 1; off < 64; off <<= 1) {
      int u = __shfl_up(incl, off);
      if (t >= off) incl += u;
    }
    if (t == blockIdx.x) bo = incl - v;
    if (blockIdx.x == 0 && t == 63) ptr[n] = incl;
  }
  const int base = blockIdx.x * 1024 + t * 4;
  int v0 = base + 0 < n ? cnt[base + 0] + 1 : 0;
  int v1 = base + 1 < n ? cnt[base + 1] + 1 : 0;
  int v2 = base + 2 < n ? cnt[base + 2] + 1 : 0;
  int v3 = base + 3 < n ? cnt[base + 3] + 1 : 0;
  const int tsum = v0 + v1 + v2 + v3;
  const int lane = t & 63, w = t >> 6;
  int incl = tsum;
#pragma unroll
  for (int off = 1; off < 64; off <<= 1) {
    int u = __shfl_up(incl, off);
    if (lane >= off) incl += u;
  }
  if (lane == 63) ws[w] = incl;
  __syncthreads();
  int excl = bo + incl - tsum;
  for (int i = 0; i < w; ++i) excl += ws[i];
  if (base + 0 < n) { ptr[base + 0] = excl; fill[base + 0] = excl; }
  excl += v0;
  if (base + 1 < n) { ptr[base + 1] = excl; fill[base + 1] = excl; }
  excl += v1;
  if (base + 2 < n) { ptr[base + 2] = excl; fill[base + 2] = excl; }
  excl += v2;
  if (base + 3 < n) { ptr[base + 3] = excl; fill[base + 3] = excl; }
}

__global__ __launch_bounds__(256) void k_scatter(const int* __restrict__ srce,
                                                 const int* __restrict__ dste,
                                                 int e, int n,
                                                 int* __restrict__ fill,
                                                 int* __restrict__ srcs) {
  int i = blockIdx.x * 256 + threadIdx.x;
  if (i < e) {
    int pos = atomicAdd(&fill[dste[i]], 1);
    srcs[pos] = srce[i];  // plain store: L2 write-allocate coalesces ~17 writes/line
  } else if (i < e + n) {
    int v = i - e;
    int pos = atomicAdd(&fill[v], 1);
    srcs[pos] = v;
  }
}

// ---------------- combined: zero cnt + x->bf16 + W1->W1T + W2->W2T ----------------
__global__ __launch_bounds__(256) void k_prep(int* __restrict__ cnt, int n,
                                              const float* __restrict__ x,
                                              unsigned short* __restrict__ xb,
                                              const float* __restrict__ W1,
                                              unsigned short* __restrict__ w1t,
                                              const float* __restrict__ W2,
                                              unsigned short* __restrict__ w2t, int n4) {
  int i = blockIdx.x * 256 + threadIdx.x;
  if (i < n) {
    cnt[i] = 0;
    return;
  }
  i -= n;
  if (i < n4) {
    float4 v = ((const float4*)x)[i];
    ushort4 o;
    o.x = f2b(v.x); o.y = f2b(v.y); o.z = f2b(v.z); o.w = f2b(v.w);
    ((ushort4*)xb)[i] = o;
    return;
  }
  i -= n4;
  if (i < 256 * 128) {
    int nn = i >> 7, k = i & 127;
    w1t[i] = f2b(W1[(size_t)k * 256 + nn]);
    return;
  }
  i -= 256 * 128;
  if (i < 256 * 256) {
    int nn = i >> 8, k = i & 255;
    w2t[i] = f2b(W2[(size_t)k * 256 + nn]);
  }
}

// ---------------- bf16 MFMA GEMM + fused attention coefficients ----------------
__global__ __launch_bounds__(256) void k_mfma(const unsigned short* __restrict__ A,
                                              const unsigned short* __restrict__ BT,
                                              unsigned short* __restrict__ C,
                                              const float* __restrict__ as_,
                                              const float* __restrict__ ad_,
                                              float* __restrict__ als,
                                              float* __restrict__ ald,
                                              int M, int Nn, int K) {
  __shared__ unsigned int Asu[128 * 20];
  __shared__ unsigned int Bsu[128 * 20];
  const int tid = threadIdx.x;
  const int bm = blockIdx.x * 128, bn = blockIdx.y * 128;
  const int w = tid >> 6, lane = tid & 63;
  const int wm = w >> 1, wn = w & 1;
  const int l16 = lane & 15, lg = lane >> 4;
  f32x4 acc[4][4] = {};
  for (int k0 = 0; k0 < K; k0 += 32) {
#pragma unroll
    for (int rep = 0; rep < 2; ++rep) {
      int ci = tid + rep * 256;
      int row = ci >> 2, cg = ci & 3;
      int ar = bm + row;
      ar = ar < M ? ar : M - 1;
      uint4 av = *(const uint4*)(A + (size_t)ar * K + k0 + cg * 8);
      *(uint4*)&Asu[row * 20 + cg * 4] = av;
      uint4 bv = *(const uint4*)(BT + (size_t)(bn + row) * K + k0 + cg * 8);
      *(uint4*)&Bsu[row * 20 + cg * 4] = bv;
    }
    __syncthreads();
    bf16x8 aF[4], bF[4];
#pragma unroll
    for (int mi = 0; mi < 4; ++mi)
      aF[mi] = *(const bf16x8*)&Asu[(wm * 64 + mi * 16 + l16) * 20 + lg * 4];
#pragma unroll
    for (int ni = 0; ni < 4; ++ni)
      bF[ni] = *(const bf16x8*)&Bsu[(wn * 64 + ni * 16 + l16) * 20 + lg * 4];
#pragma unroll
    for (int mi = 0; mi < 4; ++mi)
#pragma unroll
      for (int ni = 0; ni < 4; ++ni)
        acc[mi][ni] =
            __builtin_amdgcn_mfma_f32_16x16x32_bf16(aF[mi], bF[ni], acc[mi][ni], 0, 0, 0);
    __syncthreads();
  }
  float asv[4], adv[4];
#pragma unroll
  for (int ni = 0; ni < 4; ++ni) {
    int gcol = bn + wn * 64 + ni * 16 + l16;
    asv[ni] = as_[gcol];
    adv[ni] = ad_[gcol];
  }
  const int hb = (bn >> 5) + wn * 2;  // even head base
#pragma unroll
  for (int mi = 0; mi < 4; ++mi) {
#pragma unroll
    for (int r = 0; r < 4; ++r) {
      int grow = bm + wm * 64 + mi * 16 + lg * 4 + r;
      bool ok = grow < M;
      if (ok) {
#pragma unroll
        for (int ni = 0; ni < 4; ++ni) {
          int gcol = bn + wn * 64 + ni * 16 + l16;
          C[(size_t)grow * Nn + gcol] = f2b(acc[mi][ni][r]);
        }
      }
      float ps0 = acc[mi][0][r] * asv[0] + acc[mi][1][r] * asv[1];
      float ps1 = acc[mi][2][r] * asv[2] + acc[mi][3][r] * asv[3];
      float pd0 = acc[mi][0][r] * adv[0] + acc[mi][1][r] * adv[1];
      float pd1 = acc[mi][2][r] * adv[2] + acc[mi][3][r] * adv[3];
#pragma unroll
      for (int off = 1; off < 16; off <<= 1) {
        ps0 += __shfl_xor(ps0, off);
        ps1 += __shfl_xor(ps1, off);
        pd0 += __shfl_xor(pd0, off);
        pd1 += __shfl_xor(pd1, off);
      }
      if (ok && l16 == 0) {
        *(float2*)(als + (size_t)grow * 8 + hb) = make_float2(ps0, ps1);
        *(float2*)(ald + (size_t)grow * 8 + hb) = make_float2(pd0, pd1);
      }
    }
  }
}

// ---------------- GAT aggregation: quarter-wave per edge, software-pipelined (best: R9/R10) ----------------
__global__ __launch_bounds__(256) void k_agg(const unsigned short* __restrict__ h,
                                             const float* __restrict__ als,
                                             const float* __restrict__ ald,
                                             const int* __restrict__ ptr,
                                             const int* __restrict__ srcs,
                                             const float* __restrict__ bias,
                                             unsigned short* __restrict__ out, int n) {
  int wid = (blockIdx.x * 256 + threadIdx.x) >> 6;
  int lane = threadIdx.x & 63;
  if (wid >= n) return;
  const int beg = ptr[wid], end = ptr[wid + 1];
  const int L = lane & 15;   // channel slot: channels 16L..16L+15
  const int e = lane >> 4;   // edge slot 0..3
  const int hh = L >> 1;     // head of my 16 channels
  const float adh = ald[(size_t)wid * 8 + hh];
  float s = 0.f;
  float a0 = 0, a1 = 0, a2 = 0, a3 = 0, a4 = 0, a5 = 0, a6 = 0, a7 = 0;
  float a8 = 0, a9 = 0, aA = 0, aB = 0, aC = 0, aD = 0, aE = 0, aF = 0;
  int j = beg + e;
  int s0 = j < end ? srcs[j] : 0;
  int s1 = (j + 4) < end ? srcs[j + 4] : 0;
  const uint4* hp0 = (const uint4*)(h + (size_t)s0 * 256 + L * 16);
  uint4 c0 = hp0[0];
  uint4 c1 = hp0[1];
  float alsc = als[(size_t)s0 * 8 + hh];
  for (; j < end; j += 4) {
    int s2 = (j + 8) < end ? srcs[j + 8] : 0;
    const uint4* hp1 = (const uint4*)(h + (size_t)s1 * 256 + L * 16);
    uint4 n0 = hp1[0];
    uint4 n1 = hp1[1];
    float alsn = als[(size_t)s1 * 8 + hh];
    float lg = lrelu(alsc + adh, 0.2f);
    float wt = __expf(lg);  // m == 0: logits are O(1), no overflow possible
    s += wt;
    a0 += wt * b2f_lo(c0.x); a1 += wt * b2f_hi(c0.x);
    a2 += wt * b2f_lo(c0.y); a3 += wt * b2f_hi(c0.y);
    a4 += wt * b2f_lo(c0.z); a5 += wt * b2f_hi(c0.z);
    a6 += wt * b2f_lo(c0.w); a7 += wt * b2f_hi(c0.w);
    a8 += wt * b2f_lo(c1.x); a9 += wt * b2f_hi(c1.x);
    aA += wt * b2f_lo(c1.y); aB += wt * b2f_hi(c1.y);
    aC += wt * b2f_lo(c1.z); aD += wt * b2f_hi(c1.z);
    aE += wt * b2f_lo(c1.w); aF += wt * b2f_hi(c1.w);
    c0 = n0; c1 = n1; alsc = alsn;
    s1 = s2;
  }
  a0 += __shfl_xor(a0, 16); a0 += __shfl_xor(a0, 32);
  a1 += __shfl_xor(a1, 16); a1 += __shfl_xor(a1, 32);
  a2 += __shfl_xor(a2, 16); a2 += __shfl_xor(a2, 32);
  a3 += __shfl_xor(a3, 16); a3 += __shfl_xor(a3, 32);
  a4 += __shfl_xor(a4, 16); a4 += __shfl_xor(a4, 32);
  a5 += __shfl_xor(a5, 16); a5 += __shfl_xor(a5, 32);
  a6 += __shfl_xor(a6, 16); a6 += __shfl_xor(a6, 32);
  a7 += __shfl_xor(a7, 16); a7 += __shfl_xor(a7, 32);
  a8 += __shfl_xor(a8, 16); a8 += __shfl_xor(a8, 32);
  a9 += __shfl_xor(a9, 16); a9 += __shfl_xor(a9, 32);
  aA += __shfl_xor(aA, 16); aA += __shfl_xor(aA, 32);
  aB += __shfl_xor(aB, 16); aB += __shfl_xor(aB, 32);
  aC += __shfl_xor(aC, 16); aC += __shfl_xor(aC, 32);
  aD += __shfl_xor(aD, 16); aD += __shfl_xor(aD, 32);
  aE += __shfl_xor(aE, 16); aE += __shfl_xor(aE, 32);
  aF += __shfl_xor(aF, 16); aF += __shfl_xor(aF, 32);
  s += __shfl_xor(s, 16); s += __shfl_xor(s, 32);
  const float inv = 1.f / (s + 1e-16f);
  if (e == 0) {
    const float4* bp = (const float4*)(bias + L * 16);
    float4 b0 = bp[0], b1 = bp[1], b2 = bp[2], b3 = bp[3];
    uint4 o0, o1;
    o0.x = (unsigned int)f2b(a0 * inv + b0.x) | ((unsigned int)f2b(a1 * inv + b0.y) << 16);
    o0.y = (unsigned int)f2b(a2 * inv + b0.z) | ((unsigned int)f2b(a3 * inv + b0.w) << 16);
    o0.z = (unsigned int)f2b(a4 * inv + b1.x) | ((unsigned int)f2b(a5 * inv + b1.y) << 16);
    o0.w = (unsigned int)f2b(a6 * inv + b1.z) | ((unsigned int)f2b(a7 * inv + b1.w) << 16);
    o1.x = (unsigned int)f2b(a8 * inv + b2.x) | ((unsigned int)f2b(a9 * inv + b2.y) << 16);
    o1.y = (unsigned int)f2b(aA * inv + b2.z) | ((unsigned int)f2b(aB * inv + b2.w) << 16);
    o1.z = (unsigned int)f2b(aC * inv + b3.x) | ((unsigned int)f2b(aD * inv + b3.y) << 16);
    o1.w = (unsigned int)f2b(aE * inv + b3.z) | ((unsigned int)f2b(aF * inv + b3.w) << 16);
    uint4* op = (uint4*)(out + (size_t)wid * 256 + L * 16);
    op[0] = o0;
    op[1] = o1;
  }
}

// ---------------- BN stats pass 1: 512 blocks, 4 independent row loads in flight ----------------
__global__ __launch_bounds__(256) void k_bnp1(const unsigned short* __restrict__ x,
                                              float* __restrict__ partial, int n) {
  const int t = threadIdx.x;
  const int q = t & 63;
  const int rsub = t >> 6;
  float s0 = 0, s1 = 0, s2 = 0, s3 = 0, q0 = 0, q1 = 0, q2 = 0, q3 = 0;
  int r = blockIdx.x * 4 + rsub;
  for (; r + 6144 < n; r += 8192) {
    ushort4 va = *(const ushort4*)(x + (size_t)r * 256 + q * 4);
    ushort4 vb = *(const ushort4*)(x + (size_t)(r + 2048) * 256 + q * 4);
    ushort4 vc = *(const ushort4*)(x + (size_t)(r + 4096) * 256 + q * 4);
    ushort4 vd = *(const ushort4*)(x + (size_t)(r + 6144) * 256 + q * 4);
    float f;
    f = b2f(va.x); s0 += f; q0 += f * f;
    f = b2f(va.y); s1 += f; q1 += f * f;
    f = b2f(va.z); s2 += f; q2 += f * f;
    f = b2f(va.w); s3 += f; q3 += f * f;
    f = b2f(vb.x); s0 += f; q0 += f * f;
    f = b2f(vb.y); s1 += f; q1 += f * f;
    f = b2f(vb.z); s2 += f; q2 += f * f;
    f = b2f(vb.w); s3 += f; q3 += f * f;
    f = b2f(vc.x); s0 += f; q0 += f * f;
    f = b2f(vc.y); s1 += f; q1 += f * f;
    f = b2f(vc.z); s2 += f; q2 += f * f;
    f = b2f(vc.w); s3 += f; q3 += f * f;
    f = b2f(vd.x); s0 += f; q0 += f * f;
    f = b2f(vd.y); s1 += f; q1 += f * f;
    f = b2f(vd.z); s2 += f; q2 += f * f;
    f = b2f(vd.w); s3 += f; q3 += f * f;
  }
  for (; r < n; r += 2048) {
    ushort4 v = *(const ushort4*)(x + (size_t)r * 256 + q * 4);
    float f;
    f = b2f(v.x); s0 += f; q0 += f * f;
    f = b2f(v.y); s1 += f; q1 += f * f;
    f = b2f(v.z); s2 += f; q2 += f * f;
    f = b2f(v.w); s3 += f; q3 += f * f;
  }
  __shared__ float ls[4][512];
  ls[rsub][q * 4 + 0] = s0; ls[rsub][q * 4 + 1] = s1;
  ls[rsub][q * 4 + 2] = s2; ls[rsub][q * 4 + 3] = s3;
  ls[rsub][256 + q * 4 + 0] = q0; ls[rsub][256 + q * 4 + 1] = q1;
  ls[rsub][256 + q * 4 + 2] = q2; ls[rsub][256 + q * 4 + 3] = q3;
  __syncthreads();
  float a = ls[0][t] + ls[1][t] + ls[2][t] + ls[3][t];
  float b = ls[0][256 + t] + ls[1][256 + t] + ls[2][256 + t] + ls[3][256 + t];
  partial[blockIdx.x * 512 + t] = a;
  partial[blockIdx.x * 512 + 256 + t] = b;
}

// ---------------- BN stats pass 2: wave per channel; outputs scale/shift ----------------
__global__ __launch_bounds__(256) void k_bnp2(const float* __restrict__ partial,
                                              const float* __restrict__ ga,
                                              const float* __restrict__ be,
                                              float* __restrict__ ss, float invn) {
  const int c = blockIdx.x * 4 + (threadIdx.x >> 6);
  const int lane = threadIdx.x & 63;
  float s = 0.f, qq = 0.f;
#pragma unroll
  for (int k = 0; k < 8; ++k) {
    int b = lane + k * 64;
    s += partial[(size_t)b * 512 + c];
    qq += partial[(size_t)b * 512 + 256 + c];
  }
#pragma unroll
  for (int off = 1; off < 64; off <<= 1) {
    s += __shfl_xor(s, off);
    qq += __shfl_xor(qq, off);
  }
  if (lane == 0) {
    float mu = s * invn;
    float var = qq * invn - mu * mu;
    float sc = ga[c] * rsqrtf(var + 1e-5f);
    ss[c] = sc;
    ss[256 + c] = be[c] - mu * sc;
  }
}

// ---------------- fused BN apply + LeakyReLU -> bf16 (layer 1), scale/shift form ----------------
__global__ __launch_bounds__(256) void k_bnact(const unsigned short* __restrict__ x,
                                               const float* __restrict__ ss,
                                               unsigned short* __restrict__ out, int n) {
  const int tot4 = n * 64;
  for (int t = blockIdx.x * 256 + threadIdx.x; t < tot4; t += gridDim.x * 256) {
    int i0 = t * 4;
    int c = i0 & 255;
    ushort4 xu = *(const ushort4*)(x + i0);
    float4 scv = *(const float4*)(ss + c);
    float4 shv = *(const float4*)(ss + 256 + c);
    float t0 = b2f(xu.x) * scv.x + shv.x;
    float t1 = b2f(xu.y) * scv.y + shv.y;
    float t2 = b2f(xu.z) * scv.z + shv.z;
    float t3 = b2f(xu.w) * scv.w + shv.w;
    float o0 = fmaxf(t0, 0.01f * t0);
    float o1 = fmaxf(t1, 0.01f * t1);
    float o2 = fmaxf(t2, 0.01f * t2);
    float o3 = fmaxf(t3, 0.01f * t3);
    ushort4 ob;
    ob.x = f2b(o0); ob.y = f2b(o1); ob.z = f2b(o2); ob.w = f2b(o3);
    *(ushort4*)(out + i0) = ob;
  }
}

// ---------------- layer2 BN+LReLU+residual fused with layer3 GEMM (wave per node) ----------------
__global__ __launch_bounds__(256) void k_bnact3(const unsigned short* __restrict__ x,
                                                const float* __restrict__ ss,
                                                const unsigned short* __restrict__ res,
                                                const float* __restrict__ W3,
                                                const float* __restrict__ as3,
                                                const float* __restrict__ ad3,
                                                uint4* __restrict__ h3p, int n) {
  int wid = (blockIdx.x * 256 + threadIdx.x) >> 6;
  int lane = threadIdx.x & 63;
  if (wid >= n) return;
  const int c = lane * 4;
  ushort4 xu = *(const ushort4*)(x + (size_t)wid * 256 + c);
  ushort4 rv = *(const ushort4*)(res + (size_t)wid * 256 + c);
  float4 scv = *(const float4*)(ss + c);
  float4 shv = *(const float4*)(ss + 256 + c);
  float t0 = b2f(xu.x) * scv.x + shv.x;
  float t1 = b2f(xu.y) * scv.y + shv.y;
  float t2 = b2f(xu.z) * scv.z + shv.z;
  float t3 = b2f(xu.w) * scv.w + shv.w;
  float o0 = fmaxf(t0, 0.01f * t0) + b2f(rv.x);
  float o1 = fmaxf(t1, 0.01f * t1) + b2f(rv.y);
  float o2 = fmaxf(t2, 0.01f * t2) + b2f(rv.z);
  float o3 = fmaxf(t3, 0.01f * t3) + b2f(rv.w);
  const float4* Wp = (const float4*)W3 + lane * 4;
  float4 w0 = Wp[0], w1 = Wp[1], w2 = Wp[2], w3 = Wp[3];
  float a0 = o0 * w0.x + o1 * w1.x + o2 * w2.x + o3 * w3.x;
  float a1 = o0 * w0.y + o1 * w1.y + o2 * w2.y + o3 * w3.y;
  float a2 = o0 * w0.z + o1 * w1.z + o2 * w2.z + o3 * w3.z;
  float a3 = o0 * w0.w + o1 * w1.w + o2 * w2.w + o3 * w3.w;
#pragma unroll
  for (int off = 1; off < 64; off <<= 1) {
    a0 += __shfl_xor(a0, off);
    a1 += __shfl_xor(a1, off);
    a2 += __shfl_xor(a2, off);
    a3 += __shfl_xor(a3, off);
  }
  if (lane == 0) {
    float als3v = a0 * as3[0] + a1 * as3[1] + a2 * as3[2] + a3 * as3[3];
    float ald3v = a0 * ad3[0] + a1 * ad3[1] + a2 * ad3[2] + a3 * ad3[3];
    uint4 pv;
    pv.x = (unsigned int)f2b(a0) | ((unsigned int)f2b(a1) << 16);
    pv.y = (unsigned int)f2b(a2) | ((unsigned int)f2b(a3) << 16);
    pv.z = fbits(als3v);
    pv.w = fbits(ald3v);
    h3p[wid] = pv;
  }
}

// ---------------- layer 3 aggregation: 16 lanes/node, 4 nodes/wave -> d_out ----------------
__global__ __launch_bounds__(256) void k_agg3(const uint4* __restrict__ h3p,
                                              const int* __restrict__ ptr,
                                              const int* __restrict__ srcs,
                                              const float* __restrict__ b3,
                                              float* __restrict__ out, int n) {
  const int wv = (blockIdx.x * 256 + threadIdx.x) >> 6;
  const int lane = threadIdx.x & 63;
  const int sl = lane & 15;            // edge slot within node
  const int node = wv * 4 + (lane >> 4);
  const bool ok = node < n;
  int beg = 0, end = 0;
  float aldh = 0.f;
  if (ok) {
    beg = ptr[node];
    end = ptr[node + 1];
    aldh = bitsf(h3p[node].w);
  }
  float s = 0.f, a0 = 0.f, a1 = 0.f, a2 = 0.f, a3 = 0.f;
  for (int j = beg + sl; j < end; j += 16) {
    uint4 v = h3p[srcs[j]];
    float wgt = __expf(lrelu(bitsf(v.z) + aldh, 0.2f));  // m == 0
    s += wgt;
    a0 += wgt * b2f_lo(v.x);
    a1 += wgt * b2f_hi(v.x);
    a2 += wgt * b2f_lo(v.y);
    a3 += wgt * b2f_hi(v.y);
  }
#pragma unroll
  for (int off = 1; off < 16; off <<= 1) {
    s += __shfl_xor(s, off);
    a0 += __shfl_xor(a0, off);
    a1 += __shfl_xor(a1, off);
    a2 += __shfl_xor(a2, off);
    a3 += __shfl_xor(a3, off);
  }
  if (ok && sl == 0) {
    float inv = 1.f / (s + 1e-16f);
    float4 o;
    o.x = a0 * inv + b3[0];
    o.y = a1 * inv + b3[1];
    o.z = a2 * inv + b3[2];
    o.w = a3 * inv + b3[3];
    *(float4*)(out + (size_t)node * 4) = o;
  }
}

extern "C" void kernel_launch(void* const* d_in, const int* in_sizes, int n_in,
                              void* d_out, int out_size, void* d_ws, size_t ws_size,
                              hipStream_t stream) {
  const float* x   = (const float*)d_in[0];
  const int*   ei  = (const int*)d_in[1];
  const float* W1  = (const float*)d_in[2];
  const float* as1 = (const float*)d_in[3];
  const float* ad1 = (const float*)d_in[4];
  const float* b1  = (const float*)d_in[5];
  const float* ga1 = (const float*)d_in[6];
  const float* be1 = (const float*)d_in[7];
  const float* W2  = (const float*)d_in[8];
  const float* as2 = (const float*)d_in[9];
  const float* ad2 = (const float*)d_in[10];
  const float* b2  = (const float*)d_in[11];
  const float* ga2 = (const float*)d_in[12];
  const float* be2 = (const float*)d_in[13];
  const float* W3  = (const float*)d_in[14];
  const float* as3 = (const float*)d_in[15];
  const float* ad3 = (const float*)d_in[16];
  const float* b3  = (const float*)d_in[17];

  const int N = in_sizes[0] / 128;
  const int E = in_sizes[1] / 2;
  const int ET = E + N;
  float* out = (float*)d_out;

  char* w = (char*)d_ws;
  auto alloc = [&](size_t bytes) -> void* {
    void* p = (void*)w;
    w += (bytes + 255) & ~(size_t)255;
    return p;
  };
  int* ptr              = (int*)alloc((size_t)(N + 1) * 4);
  int* fill             = (int*)alloc((size_t)N * 4);
  int* cnt              = (int*)alloc((size_t)N * 4);
  int* bsum             = (int*)alloc(64 * 4);
  int* srcs             = (int*)alloc((size_t)ET * 4);
  unsigned short* hbuf  = (unsigned short*)alloc((size_t)N * 256 * 2);
  unsigned short* aggb  = (unsigned short*)alloc((size_t)N * 256 * 2);
  unsigned short* a1b   = (unsigned short*)alloc((size_t)N * 256 * 2);
  unsigned short* xb    = (unsigned short*)alloc((size_t)N * 128 * 2);
  unsigned short* w1t   = (unsigned short*)alloc(256 * 128 * 2);
  unsigned short* w2t   = (unsigned short*)alloc(256 * 256 * 2);
  float* als            = (float*)alloc((size_t)N * 8 * 4);
  float* ald            = (float*)alloc((size_t)N * 8 * 4);
  uint4* h3p            = (uint4*)alloc((size_t)N * 16);
  float* partial        = (float*)alloc(512 * 512 * 4);
  float* ss             = (float*)alloc(1024 * 4);  // [sc1|sh1 | sc2|sh2]

  const int* esrc = ei;
  const int* edst = ei + E;
  const float invn = 1.f / (float)N;

  // prep: zero cnt + all bf16 conversions (one launch)
  const int n4 = N * 32;
  const int prep_tot = N + n4 + 256 * 128 + 256 * 256;
  k_prep<<<(prep_tot + 255) / 256, 256, 0, stream>>>(cnt, N, x, xb, W1, w1t, W2, w2t, n4);

  // CSR (shared by all three layers)
  const int B = (N + 1023) / 1024;  // must be <= 64
  k_hist<<<(E + 255) / 256, 256, 0, stream>>>(edst, E, cnt);
  k_bsum<<<B, 256, 0, stream>>>(cnt, bsum, N);
  k_scanl<<<B, 256, 0, stream>>>(cnt, bsum, ptr, fill, N, B);
  k_scatter<<<(ET + 255) / 256, 256, 0, stream>>>(esrc, edst, E, N, fill, srcs);

  const dim3 gemm_grid((N + 127) / 128, 2);
  const int wblocks = (N + 3) / 4;
  const int wblocks4 = (N + 15) / 16;  // k_agg3: 4 nodes per wave

  // layer 1
  k_mfma<<<gemm_grid, 256, 0, stream>>>(xb, w1t, hbuf, as1, ad1, als, ald, N, 256, 128);
  k_agg<<<wblocks, 256, 0, stream>>>(hbuf, als, ald, ptr, srcs, b1, aggb, N);
  k_bnp1<<<512, 256, 0, stream>>>(aggb, partial, N);
  k_bnp2<<<64, 256, 0, stream>>>(partial, ga1, be1, ss, invn);
  k_bnact<<<2048, 256, 0, stream>>>(aggb, ss, a1b, N);

  // layer 2 (+ residual a1b)
  k_mfma<<<gemm_grid, 256, 0, stream>>>(a1b, w2t, hbuf, as2, ad2, als, ald, N, 256, 256);
  k_agg<<<wblocks, 256, 0, stream>>>(hbuf, als, ald, ptr, srcs, b2, aggb, N);
  k_bnp1<<<512, 256, 0, stream>>>(aggb, partial, N);
  k_bnp2<<<64, 256, 0, stream>>>(partial, ga2, be2, ss + 512, invn);
  k_bnact3<<<wblocks, 256, 0, stream>>>(aggb, ss + 512, a1b, W3, as3, ad3, h3p, N);

  // layer 3 aggregation -> output
  k_agg3<<<wblocks4, 256, 0, stream>>>(h3p, ptr, srcs, b3, out, N);
}